// Round 11
// baseline (610.394 us; speedup 1.0000x reference)
//
#include <hip/hip_runtime.h>
#include <math.h>

// DrBC: encoder -> 4x(aggregate ; gru_mfma) -> (aggregate ; gru_dec fused decoder).
// h/agg stored FEATURE-CHUNKED [4][N][32] bf16 so each 3.2MB chunk is L2-resident on
// its XCD pair (aggregate grid: chunk = (blockIdx%8)>>1 -> XCD-affine gather).

#define NTHREADS 256
#define SCAN_CHUNK 1024

typedef __attribute__((ext_vector_type(8))) short s16x8;
typedef __attribute__((ext_vector_type(4))) float f32x4;

union U8 { s16x8 v; ushort4 h[2]; int4 q; };

__device__ __forceinline__ unsigned short f2bf(float f) {
  union { float f; unsigned u; } x; x.f = f;
  unsigned u = x.u + 0x7FFFu + ((x.u >> 16) & 1u);  // RNE to bf16
  return (unsigned short)(u >> 16);
}
__device__ __forceinline__ float bf2f(unsigned short s) {
  union { unsigned u; float f; } x; x.u = ((unsigned)s) << 16;
  return x.f;
}

// ---------------- CSR build ----------------

__global__ void count_deg(const int* __restrict__ col, int* deg, int E) {
  int e = blockIdx.x * NTHREADS + threadIdx.x;
  if (e < E) atomicAdd(&deg[col[e]], 1);
}

__global__ void block_reduce(const int* __restrict__ cnt, int* __restrict__ bsum,
                             float* __restrict__ dinv, int n) {
  __shared__ int red[NTHREADS];
  int b = blockIdx.x, t = threadIdx.x;
  int base = b * SCAN_CHUNK + t * 4;
  int s = 0;
#pragma unroll
  for (int i = 0; i < 4; ++i) {
    int idx = base + i;
    if (idx < n) {
      int c = cnt[idx];
      s += c;
      dinv[idx] = rsqrtf((float)c + 1.0f);
    }
  }
  red[t] = s;
  __syncthreads();
  for (int off = NTHREADS / 2; off > 0; off >>= 1) {
    if (t < off) red[t] += red[t + off];
    __syncthreads();
  }
  if (t == 0) bsum[b] = red[0];
}

// 64 threads (1 wave); nb <= 64.
__global__ void scan_partials(const int* __restrict__ bsum, int* __restrict__ boff,
                              int* __restrict__ row_ptr_n, int nb) {
  int t = threadIdx.x;
  int s = (t < nb) ? bsum[t] : 0;
  int orig = s;
#pragma unroll
  for (int off = 1; off < 64; off <<= 1) {
    int v = __shfl_up(s, off);
    if (t >= off) s += v;
  }
  if (t < nb) boff[t] = s - orig;
  if (t == nb - 1) *row_ptr_n = s;
}

__global__ void scan_final(const int* __restrict__ cnt, const int* __restrict__ boff,
                           int* __restrict__ row_ptr, int* __restrict__ cursor, int n) {
  __shared__ int sums[NTHREADS];
  int b = blockIdx.x, t = threadIdx.x;
  int base = b * SCAN_CHUNK + t * 4;
  int v[4];
  int s = 0;
#pragma unroll
  for (int i = 0; i < 4; ++i) { int idx = base + i; v[i] = (idx < n) ? cnt[idx] : 0; s += v[i]; }
  sums[t] = s;
  __syncthreads();
  for (int off = 1; off < NTHREADS; off <<= 1) {
    int a = (t >= off) ? sums[t - off] : 0;
    __syncthreads();
    sums[t] += a;
    __syncthreads();
  }
  int run = boff[b] + sums[t] - s;
#pragma unroll
  for (int i = 0; i < 4; ++i) {
    int idx = base + i;
    if (idx < n) { row_ptr[idx] = run; cursor[idx] = run; }
    run += v[i];
  }
}

// scatter: src index only
__global__ void scatter_edges(const int* __restrict__ row, const int* __restrict__ col,
                              int* cursor, int* __restrict__ src, int E) {
  int e = blockIdx.x * NTHREADS + threadIdx.x;
  if (e >= E) return;
  int r = row[e], c = col[e];
  int p = atomicAdd(&cursor[c], 1);
  src[p] = r;
}

// ---------------- weight packs: MFMA B-fragment order, bf16 ----------------

__global__ void pack_weights(const float* __restrict__ w_ih, const float* __restrict__ w_hh,
                             unsigned short* __restrict__ out) {
  int idx = blockIdx.x * NTHREADS + threadIdx.x;
  if (idx >= 491520) return;
  int e = idx & 7;
  int lane = (idx >> 3) & 63;
  int ft = (idx >> 9) & 7;
  int v = idx >> 12;
  int g = v % 6;
  int u = v / 6;
  int ks = u & 3;
  int layer = u >> 2;
  int k = 32 * ks + (e & 3) + 4 * ((lane >> 4) & 3) + 16 * (e >> 2);
  int j = 16 * ft + (lane & 15);
  const float* src = (g < 3) ? w_ih : w_hh;
  int gate = g % 3;
  float val = src[(size_t)layer * 49152 + (size_t)(gate * 128 + j) * 128 + k];
  out[idx] = f2bf(val);
}

// W_hid [64][128] -> [ks][ft][lane][e] bf16
__global__ void pack_whid(const float* __restrict__ W_hid, unsigned short* __restrict__ out) {
  int idx = blockIdx.x * NTHREADS + threadIdx.x;
  if (idx >= 8192) return;
  int e = idx & 7;
  int lane = (idx >> 3) & 63;
  int ft = (idx >> 9) & 3;
  int ks = idx >> 11;
  int k = 32 * ks + (e & 3) + 4 * ((lane >> 4) & 3) + 16 * (e >> 2);
  int j = 16 * ft + (lane & 15);
  out[idx] = f2bf(W_hid[j * 128 + k]);
}

// ---------------- encoder: h0 -> chunked hb (bf16) ----------------

__global__ void encoder(const float* __restrict__ x, const float* __restrict__ W,
                        const float* __restrict__ b, unsigned short* __restrict__ hb, int n) {
  int node = blockIdx.x * 4 + (threadIdx.x >> 6);
  int lane = threadIdx.x & 63;
  if (node >= n) return;
  float x0 = x[node * 3 + 0], x1 = x[node * 3 + 1], x2 = x[node * 3 + 2];
  int j0 = lane, j1 = lane + 64;
  float v0 = fmaxf(fmaf(W[j0 * 3 + 2], x2, fmaf(W[j0 * 3 + 1], x1, fmaf(W[j0 * 3], x0, b[j0]))), 0.f);
  float v1 = fmaxf(fmaf(W[j1 * 3 + 2], x2, fmaf(W[j1 * 3 + 1], x1, fmaf(W[j1 * 3], x0, b[j1]))), 0.f);
  float ss = v0 * v0 + v1 * v1;
#pragma unroll
  for (int sh = 32; sh > 0; sh >>= 1) ss += __shfl_down(ss, sh);
  ss = __shfl(ss, 0);
  float sc = 1.0f / fmaxf(sqrtf(ss), 1e-12f);
  size_t o0 = ((size_t)(j0 >> 5) * n + node) * 32 + (j0 & 31);
  size_t o1 = ((size_t)(j1 >> 5) * n + node) * 32 + (j1 & 31);
  hb[o0] = f2bf(v0 * sc);
  hb[o1] = f2bf(v1 * sc);
}

// ---------------- aggregation: XCD-chunked gather ----------------
// grid = ceil(ceil(n/4)/2)*8 blocks; chunk = (b%8)>>1 -> XCD pair per chunk.
// Wave: lane = e*16 + f2 (e: edge slot 0..3, f2: u32 feature pair 0..15).
// agg_c[node] = dinv[node] * sum_e dinv[src] * h_c[src]

__global__ __launch_bounds__(256) void aggregate(
    const int* __restrict__ row_ptr, const int* __restrict__ srcv,
    const float* __restrict__ dinv, const unsigned short* __restrict__ hc,
    unsigned short* __restrict__ aggc, int n) {
  int b = blockIdx.x;
  int r = b & 7, g = b >> 3;
  int chunk = r >> 1;
  int sub = g * 2 + (r & 1);
  int node = sub * 4 + (threadIdx.x >> 6);
  if (node >= n) return;
  int l = threadIdx.x & 63;
  int e = l >> 4, f2 = l & 15;
  const unsigned* hw = (const unsigned*)hc + (size_t)chunk * n * 16;
  int pb = row_ptr[node], pe = row_ptr[node + 1];
  float a0A = 0.f, a1A = 0.f, a0B = 0.f, a1B = 0.f;
  int p = pb;
  for (; p + 8 <= pe; p += 8) {
    int sA = srcv[p + e];
    int sB = srcv[p + 4 + e];
    float wA = dinv[sA], wB = dinv[sB];
    unsigned uA = hw[(size_t)sA * 16 + f2];
    unsigned uB = hw[(size_t)sB * 16 + f2];
    a0A = fmaf(wA, bf2f((unsigned short)(uA & 0xFFFFu)), a0A);
    a1A = fmaf(wA, bf2f((unsigned short)(uA >> 16)), a1A);
    a0B = fmaf(wB, bf2f((unsigned short)(uB & 0xFFFFu)), a0B);
    a1B = fmaf(wB, bf2f((unsigned short)(uB >> 16)), a1B);
  }
  if (p < pe) {
    int q = p + e;
    int s = (q < pe) ? srcv[q] : srcv[pb];
    float w = (q < pe) ? dinv[s] : 0.f;
    unsigned u = hw[(size_t)s * 16 + f2];
    a0A = fmaf(w, bf2f((unsigned short)(u & 0xFFFFu)), a0A);
    a1A = fmaf(w, bf2f((unsigned short)(u >> 16)), a1A);
    if (p + 4 < pe) {
      int q2 = q + 4;
      int s2 = (q2 < pe) ? srcv[q2] : srcv[pb];
      float w2 = (q2 < pe) ? dinv[s2] : 0.f;
      unsigned u2 = hw[(size_t)s2 * 16 + f2];
      a0B = fmaf(w2, bf2f((unsigned short)(u2 & 0xFFFFu)), a0B);
      a1B = fmaf(w2, bf2f((unsigned short)(u2 >> 16)), a1B);
    }
  }
  float a0 = a0A + a0B, a1 = a1A + a1B;
  a0 += __shfl_xor(a0, 16); a0 += __shfl_xor(a0, 32);
  a1 += __shfl_xor(a1, 16); a1 += __shfl_xor(a1, 32);
  if (e == 0) {
    float dc = dinv[node];
    unsigned o = ((unsigned)f2bf(a1 * dc) << 16) | (unsigned)f2bf(a0 * dc);
    ((unsigned*)aggc)[(size_t)chunk * n * 16 + (size_t)node * 16 + f2] = o;
  }
}

// ---------------- GRU layer via MFMA (chunked I/O) ----------------
// 1024 threads = 16 waves. Block: 64 nodes x 128 features x 6 gate-GEMMs, K=128.

__global__ __launch_bounds__(1024) void gru_mfma(
    const unsigned short* __restrict__ aggc, const unsigned short* __restrict__ hbc,
    unsigned short* __restrict__ hbn,
    const int4* __restrict__ wpk, const float* __restrict__ bih,
    const float* __restrict__ bhh, int n) {
  __shared__ unsigned short aggS[64 * 132];
  __shared__ unsigned short hS[64 * 132];
  __shared__ float partS[64 * 8];
  __shared__ float scv[64];
  int tid = threadIdx.x;
  int base = blockIdx.x * 64;
  int w = tid >> 6, l = tid & 63;
  int mh = w & 1, fh = w >> 1;
  int lr = l & 15, lg = l >> 4;
  int jj = fh * 16 + lr;

#pragma unroll
  for (int rep = 0; rep < 2; ++rep) {
    int idx = tid + rep * 1024;
    int row = idx >> 5, c4 = idx & 31;
    int gr = base + row; if (gr > n - 1) gr = n - 1;
    size_t off = ((size_t)(c4 >> 3) * n + gr) * 32 + (c4 & 7) * 4;
    ushort4 ua = *(const ushort4*)(aggc + off);
    ushort4 uh = *(const ushort4*)(hbc + off);
    *(ushort4*)&aggS[row * 132 + c4 * 4] = ua;
    *(ushort4*)&hS[row * 132 + c4 * 4] = uh;
  }
  __syncthreads();

  f32x4 acc[2][6];
#pragma unroll
  for (int mt = 0; mt < 2; ++mt)
#pragma unroll
    for (int g = 0; g < 6; ++g) { acc[mt][g][0] = 0.f; acc[mt][g][1] = 0.f; acc[mt][g][2] = 0.f; acc[mt][g][3] = 0.f; }

#pragma unroll
  for (int ks = 0; ks < 4; ++ks) {
    U8 fa[2], fhh[2];
#pragma unroll
    for (int mt = 0; mt < 2; ++mt) {
      int boff = (mh * 32 + mt * 16 + lr) * 132 + ks * 32 + lg * 4;
      fa[mt].h[0] = *(const ushort4*)&aggS[boff];
      fa[mt].h[1] = *(const ushort4*)&aggS[boff + 16];
      fhh[mt].h[0] = *(const ushort4*)&hS[boff];
      fhh[mt].h[1] = *(const ushort4*)&hS[boff + 16];
    }
#pragma unroll
    for (int g = 0; g < 6; ++g) {
      U8 bw; bw.q = wpk[((ks * 6 + g) * 8 + fh) * 64 + l];
      const U8& a0 = (g < 3) ? fa[0] : fhh[0];
      const U8& a1 = (g < 3) ? fa[1] : fhh[1];
      acc[0][g] = __builtin_amdgcn_mfma_f32_16x16x32_bf16(a0.v, bw.v, acc[0][g], 0, 0, 0);
      acc[1][g] = __builtin_amdgcn_mfma_f32_16x16x32_bf16(a1.v, bw.v, acc[1][g], 0, 0, 0);
    }
  }

  float br = bih[jj], bz = bih[128 + jj], bn = bih[256 + jj];
  float cr = bhh[jj], cz = bhh[128 + jj], cn = bhh[256 + jj];
  float hn_out[2][4];
#pragma unroll
  for (int mt = 0; mt < 2; ++mt)
#pragma unroll
    for (int e = 0; e < 4; ++e) {
      int row = mh * 32 + mt * 16 + lg * 4 + e;
      float ir = acc[mt][0][e], iz = acc[mt][1][e], inn = acc[mt][2][e];
      float hr = acc[mt][3][e], hz = acc[mt][4][e], hnv = acc[mt][5][e];
      float r = 1.f / (1.f + __expf(-(ir + hr + br + cr)));
      float z = 1.f / (1.f + __expf(-(iz + hz + bz + cz)));
      float ng = tanhf(inn + bn + r * (hnv + cn));
      float hv = bf2f(hS[row * 132 + jj]);
      float hn = (1.f - z) * ng + z * hv;
      hn_out[mt][e] = hn;
      float p = hn * hn;
      p += __shfl_xor(p, 1);
      p += __shfl_xor(p, 2);
      p += __shfl_xor(p, 4);
      p += __shfl_xor(p, 8);
      if (lr == 0) partS[row * 8 + fh] = p;
    }
  __syncthreads();
  if (tid < 64) {
    float ss = 0.f;
#pragma unroll
    for (int f = 0; f < 8; ++f) ss += partS[tid * 8 + f];
    scv[tid] = 1.f / fmaxf(sqrtf(ss), 1e-12f);
  }
  __syncthreads();

#pragma unroll
  for (int mt = 0; mt < 2; ++mt)
#pragma unroll
    for (int e = 0; e < 4; ++e) {
      int row = mh * 32 + mt * 16 + lg * 4 + e;
      aggS[row * 132 + jj] = f2bf(hn_out[mt][e] * scv[row]);
    }
  __syncthreads();

#pragma unroll
  for (int rep = 0; rep < 2; ++rep) {
    int idx = tid + rep * 1024;
    int row = idx >> 5, c4 = idx & 31;
    int gr = base + row;
    if (gr < n) {
      ushort4 hv4 = *(const ushort4*)&aggS[row * 132 + c4 * 4];
      size_t off = ((size_t)(c4 >> 3) * n + gr) * 32 + (c4 & 7) * 4;
      *(ushort4*)(hbn + off) = hv4;
    }
  }
}

// ---------------- last layer: GRU + 6-layer max + decoder, fused (chunked I/O) ----------------

__global__ __launch_bounds__(1024) void gru_dec(
    const unsigned short* __restrict__ aggc, const unsigned short* __restrict__ hbc,
    const unsigned short* __restrict__ h0, const unsigned short* __restrict__ h1,
    const unsigned short* __restrict__ h2, const unsigned short* __restrict__ h3,
    const int4* __restrict__ wpk, const float* __restrict__ bih,
    const float* __restrict__ bhh,
    const int4* __restrict__ wdpk, const float* __restrict__ bh,
    const float* __restrict__ Wo, const float* __restrict__ bo,
    float* __restrict__ out, int n) {
  __shared__ unsigned short aggS[64 * 132];
  __shared__ unsigned short hS[64 * 132];
  __shared__ float partS[64 * 8];
  __shared__ float scv[64];
  int tid = threadIdx.x;
  int base = blockIdx.x * 64;
  int w = tid >> 6, l = tid & 63;
  int mh = w & 1, fh = w >> 1;
  int lr = l & 15, lg = l >> 4;
  int jj = fh * 16 + lr;

#pragma unroll
  for (int rep = 0; rep < 2; ++rep) {
    int idx = tid + rep * 1024;
    int row = idx >> 5, c4 = idx & 31;
    int gr = base + row; if (gr > n - 1) gr = n - 1;
    size_t off = ((size_t)(c4 >> 3) * n + gr) * 32 + (c4 & 7) * 4;
    ushort4 ua = *(const ushort4*)(aggc + off);
    ushort4 uh = *(const ushort4*)(hbc + off);
    *(ushort4*)&aggS[row * 132 + c4 * 4] = ua;
    *(ushort4*)&hS[row * 132 + c4 * 4] = uh;
  }
  __syncthreads();

  f32x4 acc[2][6];
#pragma unroll
  for (int mt = 0; mt < 2; ++mt)
#pragma unroll
    for (int g = 0; g < 6; ++g) { acc[mt][g][0] = 0.f; acc[mt][g][1] = 0.f; acc[mt][g][2] = 0.f; acc[mt][g][3] = 0.f; }

#pragma unroll
  for (int ks = 0; ks < 4; ++ks) {
    U8 fa[2], fhh[2];
#pragma unroll
    for (int mt = 0; mt < 2; ++mt) {
      int boff = (mh * 32 + mt * 16 + lr) * 132 + ks * 32 + lg * 4;
      fa[mt].h[0] = *(const ushort4*)&aggS[boff];
      fa[mt].h[1] = *(const ushort4*)&aggS[boff + 16];
      fhh[mt].h[0] = *(const ushort4*)&hS[boff];
      fhh[mt].h[1] = *(const ushort4*)&hS[boff + 16];
    }
#pragma unroll
    for (int g = 0; g < 6; ++g) {
      U8 bw; bw.q = wpk[((ks * 6 + g) * 8 + fh) * 64 + l];
      const U8& a0 = (g < 3) ? fa[0] : fhh[0];
      const U8& a1 = (g < 3) ? fa[1] : fhh[1];
      acc[0][g] = __builtin_amdgcn_mfma_f32_16x16x32_bf16(a0.v, bw.v, acc[0][g], 0, 0, 0);
      acc[1][g] = __builtin_amdgcn_mfma_f32_16x16x32_bf16(a1.v, bw.v, acc[1][g], 0, 0, 0);
    }
  }

  float br = bih[jj], bz = bih[128 + jj], bn = bih[256 + jj];
  float cr = bhh[jj], cz = bhh[128 + jj], cn = bhh[256 + jj];
  float hn_out[2][4];
#pragma unroll
  for (int mt = 0; mt < 2; ++mt)
#pragma unroll
    for (int e = 0; e < 4; ++e) {
      int row = mh * 32 + mt * 16 + lg * 4 + e;
      float ir = acc[mt][0][e], iz = acc[mt][1][e], inn = acc[mt][2][e];
      float hr = acc[mt][3][e], hz = acc[mt][4][e], hnv = acc[mt][5][e];
      float r = 1.f / (1.f + __expf(-(ir + hr + br + cr)));
      float z = 1.f / (1.f + __expf(-(iz + hz + bz + cz)));
      float ng = tanhf(inn + bn + r * (hnv + cn));
      float hv = bf2f(hS[row * 132 + jj]);
      float hn = (1.f - z) * ng + z * hv;
      hn_out[mt][e] = hn;
      float p = hn * hn;
      p += __shfl_xor(p, 1);
      p += __shfl_xor(p, 2);
      p += __shfl_xor(p, 4);
      p += __shfl_xor(p, 8);
      if (lr == 0) partS[row * 8 + fh] = p;
    }
  __syncthreads();
  if (tid < 64) {
    float ss = 0.f;
#pragma unroll
    for (int f = 0; f < 8; ++f) ss += partS[tid * 8 + f];
    scv[tid] = 1.f / fmaxf(sqrtf(ss), 1e-12f);
  }
  __syncthreads();

  // normalize h5 -> aggS
#pragma unroll
  for (int mt = 0; mt < 2; ++mt)
#pragma unroll
    for (int e = 0; e < 4; ++e) {
      int row = mh * 32 + mt * 16 + lg * 4 + e;
      aggS[row * 132 + jj] = f2bf(hn_out[mt][e] * scv[row]);
    }
  __syncthreads();

  // z = max(h0..h3, h4(=hS), h5(=aggS)) -> hS
  const unsigned short* hp[4] = {h0, h1, h2, h3};
#pragma unroll
  for (int rep = 0; rep < 2; ++rep) {
    int idx = tid + rep * 1024;
    int row = idx >> 5, c4 = idx & 31;
    int gr = base + row; if (gr > n - 1) gr = n - 1;
    size_t o = ((size_t)(c4 >> 3) * n + gr) * 32 + (c4 & 7) * 4;
    ushort4 m = *(const ushort4*)&aggS[row * 132 + c4 * 4];       // h5
    ushort4 u4 = *(const ushort4*)&hS[row * 132 + c4 * 4];        // h4
    m.x = (bf2f(u4.x) > bf2f(m.x)) ? u4.x : m.x;
    m.y = (bf2f(u4.y) > bf2f(m.y)) ? u4.y : m.y;
    m.z = (bf2f(u4.z) > bf2f(m.z)) ? u4.z : m.z;
    m.w = (bf2f(u4.w) > bf2f(m.w)) ? u4.w : m.w;
#pragma unroll
    for (int li = 0; li < 4; ++li) {
      ushort4 uu = *(const ushort4*)(hp[li] + o);
      m.x = (bf2f(uu.x) > bf2f(m.x)) ? uu.x : m.x;
      m.y = (bf2f(uu.y) > bf2f(m.y)) ? uu.y : m.y;
      m.z = (bf2f(uu.z) > bf2f(m.z)) ? uu.z : m.z;
      m.w = (bf2f(uu.w) > bf2f(m.w)) ? uu.w : m.w;
    }
    *(ushort4*)&hS[row * 132 + c4 * 4] = m;
  }
  __syncthreads();

  // decoder MFMA: wave w -> m-tile mq=w&3, ft tile fq=w>>2
  int mq = w & 3, fq = w >> 2;
  f32x4 dacc;
  dacc[0] = 0.f; dacc[1] = 0.f; dacc[2] = 0.f; dacc[3] = 0.f;
#pragma unroll
  for (int ks = 0; ks < 4; ++ks) {
    U8 fz;
    int boff = (mq * 16 + lr) * 132 + ks * 32 + lg * 4;
    fz.h[0] = *(const ushort4*)&hS[boff];
    fz.h[1] = *(const ushort4*)&hS[boff + 16];
    U8 bw; bw.q = wdpk[(ks * 4 + fq) * 64 + l];
    dacc = __builtin_amdgcn_mfma_f32_16x16x32_bf16(fz.v, bw.v, dacc, 0, 0, 0);
  }
  int j = fq * 16 + lr;
  float bj = bh[j], wj = Wo[j];
#pragma unroll
  for (int e = 0; e < 4; ++e) {
    float v = fmaxf(dacc[e] + bj, 0.f) * wj;
    v += __shfl_xor(v, 1);
    v += __shfl_xor(v, 2);
    v += __shfl_xor(v, 4);
    v += __shfl_xor(v, 8);
    if (lr == 0) partS[(mq * 16 + lg * 4 + e) * 4 + fq] = v;
  }
  __syncthreads();
  if (tid < 64) {
    int gr = base + tid;
    if (gr < n) {
      float o4 = (partS[tid * 4 + 0] + partS[tid * 4 + 1]) +
                 (partS[tid * 4 + 2] + partS[tid * 4 + 3]);
      out[gr] = o4 + bo[0];
    }
  }
}

// ---------------- launch ----------------

extern "C" void kernel_launch(void* const* d_in, const int* in_sizes, int n_in,
                              void* d_out, int out_size, void* d_ws, size_t ws_size,
                              hipStream_t stream) {
  const float* x       = (const float*)d_in[0];
  const int*   edge    = (const int*)d_in[1];
  const float* W_embed = (const float*)d_in[2];
  const float* b_embed = (const float*)d_in[3];
  const float* w_ih    = (const float*)d_in[4];
  const float* w_hh    = (const float*)d_in[5];
  const float* b_ih    = (const float*)d_in[6];
  const float* b_hh    = (const float*)d_in[7];
  const float* W_hid   = (const float*)d_in[8];
  const float* b_hid   = (const float*)d_in[9];
  const float* W_out   = (const float*)d_in[10];
  const float* b_out   = (const float*)d_in[11];
  float* out = (float*)d_out;

  const int N = in_sizes[0] / 3;       // 50000
  const int E = in_sizes[1] / 2;       // 600000
  const int NB = (N + SCAN_CHUNK - 1) / SCAN_CHUNK;
  const int G4 = (N + 3) / 4;
  const int gridA = ((G4 + 1) / 2) * 8;   // chunked aggregate grid

  char* ws = (char*)d_ws;
  size_t off = 0;
  auto alloc = [&](size_t bytes) -> void* {
    void* p = ws + off;
    off = (off + bytes + 511) & ~(size_t)511;
    return p;
  };
  int*   deg     = (int*)alloc((size_t)N * 4);
  float* dinv    = (float*)alloc((size_t)N * 4);
  int*   row_ptr = (int*)alloc((size_t)(N + 1) * 4);
  int*   cursor  = (int*)alloc((size_t)N * 4);
  int*   bsum    = (int*)alloc((size_t)NB * 4);
  int*   boff    = (int*)alloc((size_t)NB * 4);
  int*   srcv    = (int*)alloc((size_t)E * 4);
  unsigned short* wpack  = (unsigned short*)alloc((size_t)491520 * 2);
  unsigned short* wdpack = (unsigned short*)alloc((size_t)8192 * 2);
  unsigned short* aggb   = (unsigned short*)alloc((size_t)N * 128 * 2);
  unsigned short* hbs[5];
  for (int i = 0; i < 5; ++i) hbs[i] = (unsigned short*)alloc((size_t)N * 128 * 2);

  const int* erow = edge;
  const int* ecol = edge + E;

  hipMemsetAsync(deg, 0, (size_t)N * 4, stream);
  count_deg<<<(E + NTHREADS - 1) / NTHREADS, NTHREADS, 0, stream>>>(ecol, deg, E);
  block_reduce<<<NB, NTHREADS, 0, stream>>>(deg, bsum, dinv, N);
  scan_partials<<<1, 64, 0, stream>>>(bsum, boff, row_ptr + N, NB);
  scan_final<<<NB, NTHREADS, 0, stream>>>(deg, boff, row_ptr, cursor, N);
  scatter_edges<<<(E + NTHREADS - 1) / NTHREADS, NTHREADS, 0, stream>>>(erow, ecol, cursor, srcv, E);

  pack_weights<<<(491520 + NTHREADS - 1) / NTHREADS, NTHREADS, 0, stream>>>(w_ih, w_hh, wpack);
  pack_whid<<<32, NTHREADS, 0, stream>>>(W_hid, wdpack);

  encoder<<<(N + 3) / 4, NTHREADS, 0, stream>>>(x, W_embed, b_embed, hbs[0], N);

  for (int l = 0; l < 4; ++l) {
    aggregate<<<gridA, NTHREADS, 0, stream>>>(row_ptr, srcv, dinv, hbs[l], aggb, N);
    gru_mfma<<<(N + 63) / 64, 1024, 0, stream>>>(
        aggb, hbs[l], hbs[l + 1],
        (const int4*)(wpack + (size_t)l * 98304),
        b_ih + (size_t)l * 384, b_hh + (size_t)l * 384, N);
  }

  aggregate<<<gridA, NTHREADS, 0, stream>>>(row_ptr, srcv, dinv, hbs[4], aggb, N);
  gru_dec<<<(N + 63) / 64, 1024, 0, stream>>>(
      aggb, hbs[4], hbs[0], hbs[1], hbs[2], hbs[3],
      (const int4*)(wpack + (size_t)4 * 98304),
      b_ih + (size_t)4 * 384, b_hh + (size_t)4 * 384,
      (const int4*)wdpack, b_hid, W_out, b_out, out, N);
}

// Round 12
// 459.051 us; speedup vs baseline: 1.3297x; 1.3297x over previous
//
#include <hip/hip_runtime.h>
#include <math.h>

// DrBC: encoder -> 4x(aggregate ; gru_mfma) -> (aggregate ; gru_dec fused decoder).
// State stored PRE-SCALED: hd = dinv*h, bf16, feature-chunked [4][N][32] (3.2MB/chunk,
// L2-resident per XCD pair via chunk=(blockIdx%8)>>1). agg[c]=dinv[c]*sum hd[src]
// needs NO per-edge weight load. GRU un-scales the h-GEMM rows by rdinv=sqrt(deg+1).

#define NTHREADS 256
#define SCAN_CHUNK 1024

typedef __attribute__((ext_vector_type(8))) short s16x8;
typedef __attribute__((ext_vector_type(4))) float f32x4;

union U8 { s16x8 v; ushort4 h[2]; int4 q; };

__device__ __forceinline__ unsigned short f2bf(float f) {
  union { float f; unsigned u; } x; x.f = f;
  unsigned u = x.u + 0x7FFFu + ((x.u >> 16) & 1u);  // RNE to bf16
  return (unsigned short)(u >> 16);
}
__device__ __forceinline__ float bf2f(unsigned short s) {
  union { unsigned u; float f; } x; x.u = ((unsigned)s) << 16;
  return x.f;
}

// ---------------- CSR build ----------------

__global__ void count_deg(const int* __restrict__ col, int* deg, int E) {
  int e = blockIdx.x * NTHREADS + threadIdx.x;
  if (e < E) atomicAdd(&deg[col[e]], 1);
}

__global__ void block_reduce(const int* __restrict__ cnt, int* __restrict__ bsum,
                             float* __restrict__ dinv, float* __restrict__ rdinv, int n) {
  __shared__ int red[NTHREADS];
  int b = blockIdx.x, t = threadIdx.x;
  int base = b * SCAN_CHUNK + t * 4;
  int s = 0;
#pragma unroll
  for (int i = 0; i < 4; ++i) {
    int idx = base + i;
    if (idx < n) {
      int c = cnt[idx];
      s += c;
      dinv[idx] = rsqrtf((float)c + 1.0f);
      rdinv[idx] = sqrtf((float)c + 1.0f);
    }
  }
  red[t] = s;
  __syncthreads();
  for (int off = NTHREADS / 2; off > 0; off >>= 1) {
    if (t < off) red[t] += red[t + off];
    __syncthreads();
  }
  if (t == 0) bsum[b] = red[0];
}

// 64 threads (1 wave); nb <= 64.
__global__ void scan_partials(const int* __restrict__ bsum, int* __restrict__ boff,
                              int* __restrict__ row_ptr_n, int nb) {
  int t = threadIdx.x;
  int s = (t < nb) ? bsum[t] : 0;
  int orig = s;
#pragma unroll
  for (int off = 1; off < 64; off <<= 1) {
    int v = __shfl_up(s, off);
    if (t >= off) s += v;
  }
  if (t < nb) boff[t] = s - orig;
  if (t == nb - 1) *row_ptr_n = s;
}

__global__ void scan_final(const int* __restrict__ cnt, const int* __restrict__ boff,
                           int* __restrict__ row_ptr, int* __restrict__ cursor, int n) {
  __shared__ int sums[NTHREADS];
  int b = blockIdx.x, t = threadIdx.x;
  int base = b * SCAN_CHUNK + t * 4;
  int v[4];
  int s = 0;
#pragma unroll
  for (int i = 0; i < 4; ++i) { int idx = base + i; v[i] = (idx < n) ? cnt[idx] : 0; s += v[i]; }
  sums[t] = s;
  __syncthreads();
  for (int off = 1; off < NTHREADS; off <<= 1) {
    int a = (t >= off) ? sums[t - off] : 0;
    __syncthreads();
    sums[t] += a;
    __syncthreads();
  }
  int run = boff[b] + sums[t] - s;
#pragma unroll
  for (int i = 0; i < 4; ++i) {
    int idx = base + i;
    if (idx < n) { row_ptr[idx] = run; cursor[idx] = run; }
    run += v[i];
  }
}

// scatter: src index only
__global__ void scatter_edges(const int* __restrict__ row, const int* __restrict__ col,
                              int* cursor, int* __restrict__ src, int E) {
  int e = blockIdx.x * NTHREADS + threadIdx.x;
  if (e >= E) return;
  int r = row[e], c = col[e];
  int p = atomicAdd(&cursor[c], 1);
  src[p] = r;
}

// ---------------- weight packs: MFMA B-fragment order, bf16 ----------------

__global__ void pack_weights(const float* __restrict__ w_ih, const float* __restrict__ w_hh,
                             unsigned short* __restrict__ out) {
  int idx = blockIdx.x * NTHREADS + threadIdx.x;
  if (idx >= 491520) return;
  int e = idx & 7;
  int lane = (idx >> 3) & 63;
  int ft = (idx >> 9) & 7;
  int v = idx >> 12;
  int g = v % 6;
  int u = v / 6;
  int ks = u & 3;
  int layer = u >> 2;
  int k = 32 * ks + (e & 3) + 4 * ((lane >> 4) & 3) + 16 * (e >> 2);
  int j = 16 * ft + (lane & 15);
  const float* src = (g < 3) ? w_ih : w_hh;
  int gate = g % 3;
  float val = src[(size_t)layer * 49152 + (size_t)(gate * 128 + j) * 128 + k];
  out[idx] = f2bf(val);
}

// W_hid [64][128] -> [ks][ft][lane][e] bf16
__global__ void pack_whid(const float* __restrict__ W_hid, unsigned short* __restrict__ out) {
  int idx = blockIdx.x * NTHREADS + threadIdx.x;
  if (idx >= 8192) return;
  int e = idx & 7;
  int lane = (idx >> 3) & 63;
  int ft = (idx >> 9) & 3;
  int ks = idx >> 11;
  int k = 32 * ks + (e & 3) + 4 * ((lane >> 4) & 3) + 16 * (e >> 2);
  int j = 16 * ft + (lane & 15);
  out[idx] = f2bf(W_hid[j * 128 + k]);
}

// ---------------- encoder: hd0 = dinv * l2norm(relu(xW+b)) -> chunked bf16 ----------------

__global__ void encoder(const float* __restrict__ x, const float* __restrict__ W,
                        const float* __restrict__ b, const float* __restrict__ dinv,
                        unsigned short* __restrict__ hd, int n) {
  int node = blockIdx.x * 4 + (threadIdx.x >> 6);
  int lane = threadIdx.x & 63;
  if (node >= n) return;
  float x0 = x[node * 3 + 0], x1 = x[node * 3 + 1], x2 = x[node * 3 + 2];
  int j0 = lane, j1 = lane + 64;
  float v0 = fmaxf(fmaf(W[j0 * 3 + 2], x2, fmaf(W[j0 * 3 + 1], x1, fmaf(W[j0 * 3], x0, b[j0]))), 0.f);
  float v1 = fmaxf(fmaf(W[j1 * 3 + 2], x2, fmaf(W[j1 * 3 + 1], x1, fmaf(W[j1 * 3], x0, b[j1]))), 0.f);
  float ss = v0 * v0 + v1 * v1;
#pragma unroll
  for (int sh = 32; sh > 0; sh >>= 1) ss += __shfl_down(ss, sh);
  ss = __shfl(ss, 0);
  float sc = 1.0f / fmaxf(sqrtf(ss), 1e-12f);
  float dv = dinv[node];
  size_t o0 = ((size_t)(j0 >> 5) * n + node) * 32 + (j0 & 31);
  size_t o1 = ((size_t)(j1 >> 5) * n + node) * 32 + (j1 & 31);
  hd[o0] = f2bf(v0 * sc * dv);
  hd[o1] = f2bf(v1 * sc * dv);
}

// ---------------- aggregation: chunked, prescaled, 4 nodes/wave, MLP-4 ----------------
// grid: r=b&7 -> chunk=r>>1 (XCD pair per chunk); sub=(b>>3)*2+(r&1); 16 nodes/block.
// Wave lane = e*16+f2: e = node slot (4 nodes/wave), f2 = u32 feature col of chunk.
// agg_c[node] = dinv[node] * sum_e hd_c[src]; no cross-lane reduce needed.

__global__ __launch_bounds__(256) void aggregate(
    const int* __restrict__ row_ptr, const int* __restrict__ srcv,
    const float* __restrict__ dinv, const unsigned short* __restrict__ hd,
    unsigned short* __restrict__ aggc, int n) {
  int b = blockIdx.x;
  int r = b & 7, g = b >> 3;
  int chunk = r >> 1;
  int sub = g * 2 + (r & 1);
  int w = threadIdx.x >> 6, l = threadIdx.x & 63;
  int e = l >> 4, f2 = l & 15;
  int node = sub * 16 + w * 4 + e;
  if (node >= n) return;
  const unsigned* hw = (const unsigned*)hd + (size_t)chunk * n * 16;
  int pb = row_ptr[node], pe = row_ptr[node + 1];
  float a0[4] = {0.f, 0.f, 0.f, 0.f};
  float a1[4] = {0.f, 0.f, 0.f, 0.f};
  int p = pb;
  for (; p + 4 <= pe; p += 4) {
    int s0 = srcv[p], s1 = srcv[p + 1], s2 = srcv[p + 2], s3 = srcv[p + 3];
    unsigned u0 = hw[(size_t)s0 * 16 + f2];
    unsigned u1 = hw[(size_t)s1 * 16 + f2];
    unsigned u2 = hw[(size_t)s2 * 16 + f2];
    unsigned u3 = hw[(size_t)s3 * 16 + f2];
    a0[0] += bf2f((unsigned short)(u0 & 0xFFFFu)); a1[0] += bf2f((unsigned short)(u0 >> 16));
    a0[1] += bf2f((unsigned short)(u1 & 0xFFFFu)); a1[1] += bf2f((unsigned short)(u1 >> 16));
    a0[2] += bf2f((unsigned short)(u2 & 0xFFFFu)); a1[2] += bf2f((unsigned short)(u2 >> 16));
    a0[3] += bf2f((unsigned short)(u3 & 0xFFFFu)); a1[3] += bf2f((unsigned short)(u3 >> 16));
  }
  for (; p < pe; ++p) {
    int s = srcv[p];
    unsigned u = hw[(size_t)s * 16 + f2];
    a0[0] += bf2f((unsigned short)(u & 0xFFFFu));
    a1[0] += bf2f((unsigned short)(u >> 16));
  }
  float dc = dinv[node];
  float s0 = ((a0[0] + a0[1]) + (a0[2] + a0[3])) * dc;
  float s1 = ((a1[0] + a1[1]) + (a1[2] + a1[3])) * dc;
  unsigned o = ((unsigned)f2bf(s1) << 16) | (unsigned)f2bf(s0);
  ((unsigned*)aggc)[(size_t)chunk * n * 16 + (size_t)node * 16 + f2] = o;
}

// ---------------- GRU layer via MFMA (chunked prescaled I/O) ----------------
// 1024 threads = 16 waves, 64 nodes/block. h-GEMM runs on hd; rows un-scaled by rdinv.

__global__ __launch_bounds__(1024) void gru_mfma(
    const unsigned short* __restrict__ aggc, const unsigned short* __restrict__ hdc,
    unsigned short* __restrict__ hdn, const float* __restrict__ dinv,
    const float* __restrict__ rdinv,
    const int4* __restrict__ wpk, const float* __restrict__ bih,
    const float* __restrict__ bhh, int n) {
  __shared__ unsigned short aggS[64 * 132];
  __shared__ unsigned short hS[64 * 132];
  __shared__ float partS[64 * 8];
  __shared__ float scv[64];
  __shared__ float dS[64], rS[64];
  int tid = threadIdx.x;
  int base = blockIdx.x * 64;
  int w = tid >> 6, l = tid & 63;
  int mh = w & 1, fh = w >> 1;
  int lr = l & 15, lg = l >> 4;
  int jj = fh * 16 + lr;

  if (tid < 64) {
    int gr = base + tid; if (gr > n - 1) gr = n - 1;
    dS[tid] = dinv[gr];
    rS[tid] = rdinv[gr];
  }
#pragma unroll
  for (int rep = 0; rep < 2; ++rep) {
    int idx = tid + rep * 1024;
    int row = idx >> 5, c4 = idx & 31;
    int gr = base + row; if (gr > n - 1) gr = n - 1;
    size_t off = ((size_t)(c4 >> 3) * n + gr) * 32 + (c4 & 7) * 4;
    ushort4 ua = *(const ushort4*)(aggc + off);
    ushort4 uh = *(const ushort4*)(hdc + off);
    *(ushort4*)&aggS[row * 132 + c4 * 4] = ua;
    *(ushort4*)&hS[row * 132 + c4 * 4] = uh;
  }
  __syncthreads();

  f32x4 acc[2][6];
#pragma unroll
  for (int mt = 0; mt < 2; ++mt)
#pragma unroll
    for (int g = 0; g < 6; ++g) { acc[mt][g][0] = 0.f; acc[mt][g][1] = 0.f; acc[mt][g][2] = 0.f; acc[mt][g][3] = 0.f; }

#pragma unroll
  for (int ks = 0; ks < 4; ++ks) {
    U8 fa[2], fhh[2];
#pragma unroll
    for (int mt = 0; mt < 2; ++mt) {
      int boff = (mh * 32 + mt * 16 + lr) * 132 + ks * 32 + lg * 4;
      fa[mt].h[0] = *(const ushort4*)&aggS[boff];
      fa[mt].h[1] = *(const ushort4*)&aggS[boff + 16];
      fhh[mt].h[0] = *(const ushort4*)&hS[boff];
      fhh[mt].h[1] = *(const ushort4*)&hS[boff + 16];
    }
#pragma unroll
    for (int g = 0; g < 6; ++g) {
      U8 bw; bw.q = wpk[((ks * 6 + g) * 8 + fh) * 64 + l];
      const U8& a0 = (g < 3) ? fa[0] : fhh[0];
      const U8& a1 = (g < 3) ? fa[1] : fhh[1];
      acc[0][g] = __builtin_amdgcn_mfma_f32_16x16x32_bf16(a0.v, bw.v, acc[0][g], 0, 0, 0);
      acc[1][g] = __builtin_amdgcn_mfma_f32_16x16x32_bf16(a1.v, bw.v, acc[1][g], 0, 0, 0);
    }
  }

  float br = bih[jj], bz = bih[128 + jj], bn = bih[256 + jj];
  float cr = bhh[jj], cz = bhh[128 + jj], cn = bhh[256 + jj];
  float hn_out[2][4];
#pragma unroll
  for (int mt = 0; mt < 2; ++mt)
#pragma unroll
    for (int e = 0; e < 4; ++e) {
      int row = mh * 32 + mt * 16 + lg * 4 + e;
      float rr = rS[row];
      float ir = acc[mt][0][e], iz = acc[mt][1][e], inn = acc[mt][2][e];
      float hr = acc[mt][3][e] * rr, hz = acc[mt][4][e] * rr, hnv = acc[mt][5][e] * rr;
      float r = 1.f / (1.f + __expf(-(ir + hr + br + cr)));
      float z = 1.f / (1.f + __expf(-(iz + hz + bz + cz)));
      float ng = tanhf(inn + bn + r * (hnv + cn));
      float hv = bf2f(hS[row * 132 + jj]) * rr;
      float hn = (1.f - z) * ng + z * hv;
      hn_out[mt][e] = hn;
      float p = hn * hn;
      p += __shfl_xor(p, 1);
      p += __shfl_xor(p, 2);
      p += __shfl_xor(p, 4);
      p += __shfl_xor(p, 8);
      if (lr == 0) partS[row * 8 + fh] = p;
    }
  __syncthreads();
  if (tid < 64) {
    float ss = 0.f;
#pragma unroll
    for (int f = 0; f < 8; ++f) ss += partS[tid * 8 + f];
    scv[tid] = 1.f / fmaxf(sqrtf(ss), 1e-12f);
  }
  __syncthreads();

  // normalize + prescale -> bf16 staged into dead aggS
#pragma unroll
  for (int mt = 0; mt < 2; ++mt)
#pragma unroll
    for (int e = 0; e < 4; ++e) {
      int row = mh * 32 + mt * 16 + lg * 4 + e;
      aggS[row * 132 + jj] = f2bf(hn_out[mt][e] * scv[row] * dS[row]);
    }
  __syncthreads();

#pragma unroll
  for (int rep = 0; rep < 2; ++rep) {
    int idx = tid + rep * 1024;
    int row = idx >> 5, c4 = idx & 31;
    int gr = base + row;
    if (gr < n) {
      ushort4 hv4 = *(const ushort4*)&aggS[row * 132 + c4 * 4];
      size_t off = ((size_t)(c4 >> 3) * n + gr) * 32 + (c4 & 7) * 4;
      *(ushort4*)(hdn + off) = hv4;
    }
  }
}

// ---------------- last layer: GRU + hd-max + decoder (un-scale in epilogue) ----------------

__global__ __launch_bounds__(1024) void gru_dec(
    const unsigned short* __restrict__ aggc, const unsigned short* __restrict__ hdc,
    const unsigned short* __restrict__ h0, const unsigned short* __restrict__ h1,
    const unsigned short* __restrict__ h2, const unsigned short* __restrict__ h3,
    const float* __restrict__ dinv, const float* __restrict__ rdinv,
    const int4* __restrict__ wpk, const float* __restrict__ bih,
    const float* __restrict__ bhh,
    const int4* __restrict__ wdpk, const float* __restrict__ bh,
    const float* __restrict__ Wo, const float* __restrict__ bo,
    float* __restrict__ out, int n) {
  __shared__ unsigned short aggS[64 * 132];
  __shared__ unsigned short hS[64 * 132];
  __shared__ float partS[64 * 8];
  __shared__ float scv[64];
  __shared__ float dS[64], rS[64];
  int tid = threadIdx.x;
  int base = blockIdx.x * 64;
  int w = tid >> 6, l = tid & 63;
  int mh = w & 1, fh = w >> 1;
  int lr = l & 15, lg = l >> 4;
  int jj = fh * 16 + lr;

  if (tid < 64) {
    int gr = base + tid; if (gr > n - 1) gr = n - 1;
    dS[tid] = dinv[gr];
    rS[tid] = rdinv[gr];
  }
#pragma unroll
  for (int rep = 0; rep < 2; ++rep) {
    int idx = tid + rep * 1024;
    int row = idx >> 5, c4 = idx & 31;
    int gr = base + row; if (gr > n - 1) gr = n - 1;
    size_t off = ((size_t)(c4 >> 3) * n + gr) * 32 + (c4 & 7) * 4;
    ushort4 ua = *(const ushort4*)(aggc + off);
    ushort4 uh = *(const ushort4*)(hdc + off);
    *(ushort4*)&aggS[row * 132 + c4 * 4] = ua;
    *(ushort4*)&hS[row * 132 + c4 * 4] = uh;
  }
  __syncthreads();

  f32x4 acc[2][6];
#pragma unroll
  for (int mt = 0; mt < 2; ++mt)
#pragma unroll
    for (int g = 0; g < 6; ++g) { acc[mt][g][0] = 0.f; acc[mt][g][1] = 0.f; acc[mt][g][2] = 0.f; acc[mt][g][3] = 0.f; }

#pragma unroll
  for (int ks = 0; ks < 4; ++ks) {
    U8 fa[2], fhh[2];
#pragma unroll
    for (int mt = 0; mt < 2; ++mt) {
      int boff = (mh * 32 + mt * 16 + lr) * 132 + ks * 32 + lg * 4;
      fa[mt].h[0] = *(const ushort4*)&aggS[boff];
      fa[mt].h[1] = *(const ushort4*)&aggS[boff + 16];
      fhh[mt].h[0] = *(const ushort4*)&hS[boff];
      fhh[mt].h[1] = *(const ushort4*)&hS[boff + 16];
    }
#pragma unroll
    for (int g = 0; g < 6; ++g) {
      U8 bw; bw.q = wpk[((ks * 6 + g) * 8 + fh) * 64 + l];
      const U8& a0 = (g < 3) ? fa[0] : fhh[0];
      const U8& a1 = (g < 3) ? fa[1] : fhh[1];
      acc[0][g] = __builtin_amdgcn_mfma_f32_16x16x32_bf16(a0.v, bw.v, acc[0][g], 0, 0, 0);
      acc[1][g] = __builtin_amdgcn_mfma_f32_16x16x32_bf16(a1.v, bw.v, acc[1][g], 0, 0, 0);
    }
  }

  float br = bih[jj], bz = bih[128 + jj], bn = bih[256 + jj];
  float cr = bhh[jj], cz = bhh[128 + jj], cn = bhh[256 + jj];
  float hn_out[2][4];
#pragma unroll
  for (int mt = 0; mt < 2; ++mt)
#pragma unroll
    for (int e = 0; e < 4; ++e) {
      int row = mh * 32 + mt * 16 + lg * 4 + e;
      float rr = rS[row];
      float ir = acc[mt][0][e], iz = acc[mt][1][e], inn = acc[mt][2][e];
      float hr = acc[mt][3][e] * rr, hz = acc[mt][4][e] * rr, hnv = acc[mt][5][e] * rr;
      float r = 1.f / (1.f + __expf(-(ir + hr + br + cr)));
      float z = 1.f / (1.f + __expf(-(iz + hz + bz + cz)));
      float ng = tanhf(inn + bn + r * (hnv + cn));
      float hv = bf2f(hS[row * 132 + jj]) * rr;
      float hn = (1.f - z) * ng + z * hv;
      hn_out[mt][e] = hn;
      float p = hn * hn;
      p += __shfl_xor(p, 1);
      p += __shfl_xor(p, 2);
      p += __shfl_xor(p, 4);
      p += __shfl_xor(p, 8);
      if (lr == 0) partS[row * 8 + fh] = p;
    }
  __syncthreads();
  if (tid < 64) {
    float ss = 0.f;
#pragma unroll
    for (int f = 0; f < 8; ++f) ss += partS[tid * 8 + f];
    scv[tid] = 1.f / fmaxf(sqrtf(ss), 1e-12f);
  }
  __syncthreads();

  // hd5 = dinv * h5norm -> aggS
#pragma unroll
  for (int mt = 0; mt < 2; ++mt)
#pragma unroll
    for (int e = 0; e < 4; ++e) {
      int row = mh * 32 + mt * 16 + lg * 4 + e;
      aggS[row * 132 + jj] = f2bf(hn_out[mt][e] * scv[row] * dS[row]);
    }
  __syncthreads();

  // hd-max over hd0..hd5 -> hS (per-node dinv constant -> max commutes)
  const unsigned short* hp[4] = {h0, h1, h2, h3};
#pragma unroll
  for (int rep = 0; rep < 2; ++rep) {
    int idx = tid + rep * 1024;
    int row = idx >> 5, c4 = idx & 31;
    int gr = base + row; if (gr > n - 1) gr = n - 1;
    size_t o = ((size_t)(c4 >> 3) * n + gr) * 32 + (c4 & 7) * 4;
    ushort4 m = *(const ushort4*)&aggS[row * 132 + c4 * 4];       // hd5
    ushort4 u4 = *(const ushort4*)&hS[row * 132 + c4 * 4];        // hd4
    m.x = (bf2f(u4.x) > bf2f(m.x)) ? u4.x : m.x;
    m.y = (bf2f(u4.y) > bf2f(m.y)) ? u4.y : m.y;
    m.z = (bf2f(u4.z) > bf2f(m.z)) ? u4.z : m.z;
    m.w = (bf2f(u4.w) > bf2f(m.w)) ? u4.w : m.w;
#pragma unroll
    for (int li = 0; li < 4; ++li) {
      ushort4 uu = *(const ushort4*)(hp[li] + o);
      m.x = (bf2f(uu.x) > bf2f(m.x)) ? uu.x : m.x;
      m.y = (bf2f(uu.y) > bf2f(m.y)) ? uu.y : m.y;
      m.z = (bf2f(uu.z) > bf2f(m.z)) ? uu.z : m.z;
      m.w = (bf2f(uu.w) > bf2f(m.w)) ? uu.w : m.w;
    }
    *(ushort4*)&hS[row * 132 + c4 * 4] = m;
  }
  __syncthreads();

  // decoder MFMA on hd-max; un-scale rows by rdinv in epilogue
  int mq = w & 3, fq = w >> 2;
  f32x4 dacc;
  dacc[0] = 0.f; dacc[1] = 0.f; dacc[2] = 0.f; dacc[3] = 0.f;
#pragma unroll
  for (int ks = 0; ks < 4; ++ks) {
    U8 fz;
    int boff = (mq * 16 + lr) * 132 + ks * 32 + lg * 4;
    fz.h[0] = *(const ushort4*)&hS[boff];
    fz.h[1] = *(const ushort4*)&hS[boff + 16];
    U8 bw; bw.q = wdpk[(ks * 4 + fq) * 64 + l];
    dacc = __builtin_amdgcn_mfma_f32_16x16x32_bf16(fz.v, bw.v, dacc, 0, 0, 0);
  }
  int j = fq * 16 + lr;
  float bj = bh[j], wj = Wo[j];
#pragma unroll
  for (int e = 0; e < 4; ++e) {
    int row = mq * 16 + lg * 4 + e;
    float v = fmaxf(dacc[e] * rS[row] + bj, 0.f) * wj;
    v += __shfl_xor(v, 1);
    v += __shfl_xor(v, 2);
    v += __shfl_xor(v, 4);
    v += __shfl_xor(v, 8);
    if (lr == 0) partS[row * 4 + fq] = v;
  }
  __syncthreads();
  if (tid < 64) {
    int gr = base + tid;
    if (gr < n) {
      float o4 = (partS[tid * 4 + 0] + partS[tid * 4 + 1]) +
                 (partS[tid * 4 + 2] + partS[tid * 4 + 3]);
      out[gr] = o4 + bo[0];
    }
  }
}

// ---------------- launch ----------------

extern "C" void kernel_launch(void* const* d_in, const int* in_sizes, int n_in,
                              void* d_out, int out_size, void* d_ws, size_t ws_size,
                              hipStream_t stream) {
  const float* x       = (const float*)d_in[0];
  const int*   edge    = (const int*)d_in[1];
  const float* W_embed = (const float*)d_in[2];
  const float* b_embed = (const float*)d_in[3];
  const float* w_ih    = (const float*)d_in[4];
  const float* w_hh    = (const float*)d_in[5];
  const float* b_ih    = (const float*)d_in[6];
  const float* b_hh    = (const float*)d_in[7];
  const float* W_hid   = (const float*)d_in[8];
  const float* b_hid   = (const float*)d_in[9];
  const float* W_out   = (const float*)d_in[10];
  const float* b_out   = (const float*)d_in[11];
  float* out = (float*)d_out;

  const int N = in_sizes[0] / 3;       // 50000
  const int E = in_sizes[1] / 2;       // 600000
  const int NB = (N + SCAN_CHUNK - 1) / SCAN_CHUNK;
  const int G16 = (N + 15) / 16;
  const int gridA = ((G16 + 1) / 2) * 8;

  char* ws = (char*)d_ws;
  size_t off = 0;
  auto alloc = [&](size_t bytes) -> void* {
    void* p = ws + off;
    off = (off + bytes + 511) & ~(size_t)511;
    return p;
  };
  int*   deg     = (int*)alloc((size_t)N * 4);
  float* dinv    = (float*)alloc((size_t)N * 4);
  float* rdinv   = (float*)alloc((size_t)N * 4);
  int*   row_ptr = (int*)alloc((size_t)(N + 1) * 4);
  int*   cursor  = (int*)alloc((size_t)N * 4);
  int*   bsum    = (int*)alloc((size_t)NB * 4);
  int*   boff    = (int*)alloc((size_t)NB * 4);
  int*   srcv    = (int*)alloc((size_t)E * 4);
  unsigned short* wpack  = (unsigned short*)alloc((size_t)491520 * 2);
  unsigned short* wdpack = (unsigned short*)alloc((size_t)8192 * 2);
  unsigned short* aggb   = (unsigned short*)alloc((size_t)N * 128 * 2);
  unsigned short* hbs[5];
  for (int i = 0; i < 5; ++i) hbs[i] = (unsigned short*)alloc((size_t)N * 128 * 2);

  const int* erow = edge;
  const int* ecol = edge + E;

  hipMemsetAsync(deg, 0, (size_t)N * 4, stream);
  count_deg<<<(E + NTHREADS - 1) / NTHREADS, NTHREADS, 0, stream>>>(ecol, deg, E);
  block_reduce<<<NB, NTHREADS, 0, stream>>>(deg, bsum, dinv, rdinv, N);
  scan_partials<<<1, 64, 0, stream>>>(bsum, boff, row_ptr + N, NB);
  scan_final<<<NB, NTHREADS, 0, stream>>>(deg, boff, row_ptr, cursor, N);
  scatter_edges<<<(E + NTHREADS - 1) / NTHREADS, NTHREADS, 0, stream>>>(erow, ecol, cursor, srcv, E);

  pack_weights<<<(491520 + NTHREADS - 1) / NTHREADS, NTHREADS, 0, stream>>>(w_ih, w_hh, wpack);
  pack_whid<<<32, NTHREADS, 0, stream>>>(W_hid, wdpack);

  encoder<<<(N + 3) / 4, NTHREADS, 0, stream>>>(x, W_embed, b_embed, dinv, hbs[0], N);

  for (int l = 0; l < 4; ++l) {
    aggregate<<<gridA, NTHREADS, 0, stream>>>(row_ptr, srcv, dinv, hbs[l], aggb, N);
    gru_mfma<<<(N + 63) / 64, 1024, 0, stream>>>(
        aggb, hbs[l], hbs[l + 1], dinv, rdinv,
        (const int4*)(wpack + (size_t)l * 98304),
        b_ih + (size_t)l * 384, b_hh + (size_t)l * 384, N);
  }

  aggregate<<<gridA, NTHREADS, 0, stream>>>(row_ptr, srcv, dinv, hbs[4], aggb, N);
  gru_dec<<<(N + 63) / 64, 1024, 0, stream>>>(
      aggb, hbs[4], hbs[0], hbs[1], hbs[2], hbs[3], dinv, rdinv,
      (const int4*)(wpack + (size_t)4 * 98304),
      b_ih + (size_t)4 * 384, b_hh + (size_t)4 * 384,
      (const int4*)wdpack, b_hid, W_out, b_out, out, N);
}

// Round 13
// 414.399 us; speedup vs baseline: 1.4730x; 1.1078x over previous
//
#include <hip/hip_runtime.h>
#include <math.h>

// DrBC: encoder -> 5x(aggregate ; gru_mfma) -> decoder(6-layer max + MFMA).
// FLAT layout [N][128] bf16 (row gather = minimal transactions), state PRE-SCALED
// hd = dinv*h so aggregate is a pure row-sum (no per-edge weight loads); GRU and
// decoder un-scale rows by rdinv = sqrt(deg+1). CSR stores src only.

#define NTHREADS 256
#define SCAN_CHUNK 1024

typedef __attribute__((ext_vector_type(8))) short s16x8;
typedef __attribute__((ext_vector_type(4))) float f32x4;

union U8 { s16x8 v; ushort4 h[2]; int4 q; };

__device__ __forceinline__ unsigned short f2bf(float f) {
  union { float f; unsigned u; } x; x.f = f;
  unsigned u = x.u + 0x7FFFu + ((x.u >> 16) & 1u);  // RNE to bf16
  return (unsigned short)(u >> 16);
}
__device__ __forceinline__ float bf2f(unsigned short s) {
  union { unsigned u; float f; } x; x.u = ((unsigned)s) << 16;
  return x.f;
}

// ---------------- CSR build ----------------

__global__ void count_deg(const int* __restrict__ col, int* deg, int E) {
  int e = blockIdx.x * NTHREADS + threadIdx.x;
  if (e < E) atomicAdd(&deg[col[e]], 1);
}

__global__ void block_reduce(const int* __restrict__ cnt, int* __restrict__ bsum,
                             float* __restrict__ dinv, float* __restrict__ rdinv, int n) {
  __shared__ int red[NTHREADS];
  int b = blockIdx.x, t = threadIdx.x;
  int base = b * SCAN_CHUNK + t * 4;
  int s = 0;
#pragma unroll
  for (int i = 0; i < 4; ++i) {
    int idx = base + i;
    if (idx < n) {
      int c = cnt[idx];
      s += c;
      dinv[idx] = rsqrtf((float)c + 1.0f);
      rdinv[idx] = sqrtf((float)c + 1.0f);
    }
  }
  red[t] = s;
  __syncthreads();
  for (int off = NTHREADS / 2; off > 0; off >>= 1) {
    if (t < off) red[t] += red[t + off];
    __syncthreads();
  }
  if (t == 0) bsum[b] = red[0];
}

// 64 threads (1 wave); nb <= 64.
__global__ void scan_partials(const int* __restrict__ bsum, int* __restrict__ boff,
                              int* __restrict__ row_ptr_n, int nb) {
  int t = threadIdx.x;
  int s = (t < nb) ? bsum[t] : 0;
  int orig = s;
#pragma unroll
  for (int off = 1; off < 64; off <<= 1) {
    int v = __shfl_up(s, off);
    if (t >= off) s += v;
  }
  if (t < nb) boff[t] = s - orig;
  if (t == nb - 1) *row_ptr_n = s;
}

__global__ void scan_final(const int* __restrict__ cnt, const int* __restrict__ boff,
                           int* __restrict__ row_ptr, int* __restrict__ cursor, int n) {
  __shared__ int sums[NTHREADS];
  int b = blockIdx.x, t = threadIdx.x;
  int base = b * SCAN_CHUNK + t * 4;
  int v[4];
  int s = 0;
#pragma unroll
  for (int i = 0; i < 4; ++i) { int idx = base + i; v[i] = (idx < n) ? cnt[idx] : 0; s += v[i]; }
  sums[t] = s;
  __syncthreads();
  for (int off = 1; off < NTHREADS; off <<= 1) {
    int a = (t >= off) ? sums[t - off] : 0;
    __syncthreads();
    sums[t] += a;
    __syncthreads();
  }
  int run = boff[b] + sums[t] - s;
#pragma unroll
  for (int i = 0; i < 4; ++i) {
    int idx = base + i;
    if (idx < n) { row_ptr[idx] = run; cursor[idx] = run; }
    run += v[i];
  }
}

// scatter: src index only (weights fully factorized into prescaled state)
__global__ void scatter_edges(const int* __restrict__ row, const int* __restrict__ col,
                              int* cursor, int* __restrict__ src, int E) {
  int e = blockIdx.x * NTHREADS + threadIdx.x;
  if (e >= E) return;
  int r = row[e], c = col[e];
  int p = atomicAdd(&cursor[c], 1);
  src[p] = r;
}

// ---------------- weight packs: MFMA B-fragment order, bf16 ----------------
// k-map sigma(e,lane) = 32*ks + (e&3) + 4*((lane>>4)&3) + 16*(e>>2); same map on the
// A side -> result invariant to sigma's exact correctness.

__global__ void pack_weights(const float* __restrict__ w_ih, const float* __restrict__ w_hh,
                             unsigned short* __restrict__ out) {
  int idx = blockIdx.x * NTHREADS + threadIdx.x;
  if (idx >= 491520) return;
  int e = idx & 7;
  int lane = (idx >> 3) & 63;
  int ft = (idx >> 9) & 7;
  int v = idx >> 12;
  int g = v % 6;
  int u = v / 6;
  int ks = u & 3;
  int layer = u >> 2;
  int k = 32 * ks + (e & 3) + 4 * ((lane >> 4) & 3) + 16 * (e >> 2);
  int j = 16 * ft + (lane & 15);
  const float* src = (g < 3) ? w_ih : w_hh;
  int gate = g % 3;
  float val = src[(size_t)layer * 49152 + (size_t)(gate * 128 + j) * 128 + k];
  out[idx] = f2bf(val);
}

// W_hid [64][128] -> [ks][ft][lane][e] bf16
__global__ void pack_whid(const float* __restrict__ W_hid, unsigned short* __restrict__ out) {
  int idx = blockIdx.x * NTHREADS + threadIdx.x;
  if (idx >= 8192) return;
  int e = idx & 7;
  int lane = (idx >> 3) & 63;
  int ft = (idx >> 9) & 3;
  int ks = idx >> 11;
  int k = 32 * ks + (e & 3) + 4 * ((lane >> 4) & 3) + 16 * (e >> 2);
  int j = 16 * ft + (lane & 15);
  out[idx] = f2bf(W_hid[j * 128 + k]);
}

// ---------------- encoder: hd0 = dinv * l2norm(relu(xW+b)) (flat bf16) ----------------

__global__ void encoder(const float* __restrict__ x, const float* __restrict__ W,
                        const float* __restrict__ b, const float* __restrict__ dinv,
                        unsigned short* __restrict__ hd, int n) {
  int node = blockIdx.x * 4 + (threadIdx.x >> 6);
  int lane = threadIdx.x & 63;
  if (node >= n) return;
  float x0 = x[node * 3 + 0], x1 = x[node * 3 + 1], x2 = x[node * 3 + 2];
  int j0 = lane, j1 = lane + 64;
  float v0 = fmaxf(fmaf(W[j0 * 3 + 2], x2, fmaf(W[j0 * 3 + 1], x1, fmaf(W[j0 * 3], x0, b[j0]))), 0.f);
  float v1 = fmaxf(fmaf(W[j1 * 3 + 2], x2, fmaf(W[j1 * 3 + 1], x1, fmaf(W[j1 * 3], x0, b[j1]))), 0.f);
  float ss = v0 * v0 + v1 * v1;
#pragma unroll
  for (int sh = 32; sh > 0; sh >>= 1) ss += __shfl_down(ss, sh);
  ss = __shfl(ss, 0);
  float sc = 1.0f / fmaxf(sqrtf(ss), 1e-12f);
  float dv = dinv[node];
  size_t base = (size_t)node * 128;
  hd[base + j0] = f2bf(v0 * sc * dv);
  hd[base + j1] = f2bf(v1 * sc * dv);
}

// ---------------- aggregation: flat row gather, uniform clamped 8-batches ----------------
// agg[c] = dinv[c] * sum_e hd[src_e]   (no per-edge weights: state is prescaled)

__global__ void aggregate(const int* __restrict__ row_ptr, const int* __restrict__ src,
                          const float* __restrict__ dinv, const unsigned short* __restrict__ hd,
                          unsigned short* __restrict__ aggb, int n) {
  int node = blockIdx.x * 4 + (threadIdx.x >> 6);
  int lane = threadIdx.x & 63;
  if (node >= n) return;
  const unsigned* hw = (const unsigned*)hd;
  int pb = row_ptr[node], pe = row_ptr[node + 1];
  float aL[4] = {0.f, 0.f, 0.f, 0.f};
  float aH[4] = {0.f, 0.f, 0.f, 0.f};
  for (int p = pb; p < pe; p += 8) {
    unsigned u[8]; float wv[8];
#pragma unroll
    for (int i = 0; i < 8; ++i) {
      int q = p + i;
      int ok = q < pe;
      int s = src[ok ? q : pb];
      wv[i] = ok ? 1.f : 0.f;
      u[i] = hw[(size_t)s * 64 + lane];
    }
#pragma unroll
    for (int i = 0; i < 8; ++i) {
      aL[i & 3] = fmaf(wv[i], bf2f((unsigned short)(u[i] & 0xFFFFu)), aL[i & 3]);
      aH[i & 3] = fmaf(wv[i], bf2f((unsigned short)(u[i] >> 16)), aH[i & 3]);
    }
  }
  float dc = dinv[node];
  float a0 = ((aL[0] + aL[1]) + (aL[2] + aL[3])) * dc;
  float a1 = ((aH[0] + aH[1]) + (aH[2] + aH[3])) * dc;
  unsigned o = ((unsigned)f2bf(a1) << 16) | (unsigned)f2bf(a0);
  ((unsigned*)(aggb + (size_t)node * 128))[lane] = o;
}

// ---------------- GRU layer via MFMA (flat prescaled I/O) ----------------
// 1024 threads = 16 waves, 64 nodes/block. h-GEMM runs on hd; rows un-scaled by rdinv.

__global__ __launch_bounds__(1024) void gru_mfma(
    const unsigned short* __restrict__ aggb, const unsigned short* __restrict__ hdc,
    unsigned short* __restrict__ hdn, const float* __restrict__ dinv,
    const float* __restrict__ rdinv,
    const int4* __restrict__ wpk, const float* __restrict__ bih,
    const float* __restrict__ bhh, int n) {
  __shared__ unsigned short aggS[64 * 132];
  __shared__ unsigned short hS[64 * 132];
  __shared__ float partS[64 * 8];
  __shared__ float scv[64];
  __shared__ float dS[64], rS[64];
  int tid = threadIdx.x;
  int base = blockIdx.x * 64;
  int w = tid >> 6, l = tid & 63;
  int mh = w & 1, fh = w >> 1;
  int lr = l & 15, lg = l >> 4;
  int jj = fh * 16 + lr;

  if (tid < 64) {
    int gr = base + tid; if (gr > n - 1) gr = n - 1;
    dS[tid] = dinv[gr];
    rS[tid] = rdinv[gr];
  }
#pragma unroll
  for (int rep = 0; rep < 2; ++rep) {
    int idx = tid + rep * 1024;
    int row = idx >> 5, c4 = idx & 31;
    int gr = base + row; if (gr > n - 1) gr = n - 1;
    ushort4 ua = *(const ushort4*)(aggb + (size_t)gr * 128 + c4 * 4);
    ushort4 uh = *(const ushort4*)(hdc + (size_t)gr * 128 + c4 * 4);
    *(ushort4*)&aggS[row * 132 + c4 * 4] = ua;
    *(ushort4*)&hS[row * 132 + c4 * 4] = uh;
  }
  __syncthreads();

  f32x4 acc[2][6];
#pragma unroll
  for (int mt = 0; mt < 2; ++mt)
#pragma unroll
    for (int g = 0; g < 6; ++g) { acc[mt][g][0] = 0.f; acc[mt][g][1] = 0.f; acc[mt][g][2] = 0.f; acc[mt][g][3] = 0.f; }

#pragma unroll
  for (int ks = 0; ks < 4; ++ks) {
    U8 fa[2], fhh[2];
#pragma unroll
    for (int mt = 0; mt < 2; ++mt) {
      int boff = (mh * 32 + mt * 16 + lr) * 132 + ks * 32 + lg * 4;
      fa[mt].h[0] = *(const ushort4*)&aggS[boff];
      fa[mt].h[1] = *(const ushort4*)&aggS[boff + 16];
      fhh[mt].h[0] = *(const ushort4*)&hS[boff];
      fhh[mt].h[1] = *(const ushort4*)&hS[boff + 16];
    }
#pragma unroll
    for (int g = 0; g < 6; ++g) {
      U8 bw; bw.q = wpk[((ks * 6 + g) * 8 + fh) * 64 + l];
      const U8& a0 = (g < 3) ? fa[0] : fhh[0];
      const U8& a1 = (g < 3) ? fa[1] : fhh[1];
      acc[0][g] = __builtin_amdgcn_mfma_f32_16x16x32_bf16(a0.v, bw.v, acc[0][g], 0, 0, 0);
      acc[1][g] = __builtin_amdgcn_mfma_f32_16x16x32_bf16(a1.v, bw.v, acc[1][g], 0, 0, 0);
    }
  }

  float br = bih[jj], bz = bih[128 + jj], bn = bih[256 + jj];
  float cr = bhh[jj], cz = bhh[128 + jj], cn = bhh[256 + jj];
  float hn_out[2][4];
#pragma unroll
  for (int mt = 0; mt < 2; ++mt)
#pragma unroll
    for (int e = 0; e < 4; ++e) {
      int row = mh * 32 + mt * 16 + lg * 4 + e;
      float rr = rS[row];
      float ir = acc[mt][0][e], iz = acc[mt][1][e], inn = acc[mt][2][e];
      float hr = acc[mt][3][e] * rr, hz = acc[mt][4][e] * rr, hnv = acc[mt][5][e] * rr;
      float r = 1.f / (1.f + __expf(-(ir + hr + br + cr)));
      float z = 1.f / (1.f + __expf(-(iz + hz + bz + cz)));
      float ng = tanhf(inn + bn + r * (hnv + cn));
      float hv = bf2f(hS[row * 132 + jj]) * rr;
      float hn = (1.f - z) * ng + z * hv;
      hn_out[mt][e] = hn;
      float p = hn * hn;
      p += __shfl_xor(p, 1);
      p += __shfl_xor(p, 2);
      p += __shfl_xor(p, 4);
      p += __shfl_xor(p, 8);
      if (lr == 0) partS[row * 8 + fh] = p;
    }
  __syncthreads();
  if (tid < 64) {
    float ss = 0.f;
#pragma unroll
    for (int f = 0; f < 8; ++f) ss += partS[tid * 8 + f];
    scv[tid] = 1.f / fmaxf(sqrtf(ss), 1e-12f);
  }
  __syncthreads();

  // normalize + prescale -> bf16 staged into dead aggS
#pragma unroll
  for (int mt = 0; mt < 2; ++mt)
#pragma unroll
    for (int e = 0; e < 4; ++e) {
      int row = mh * 32 + mt * 16 + lg * 4 + e;
      aggS[row * 132 + jj] = f2bf(hn_out[mt][e] * scv[row] * dS[row]);
    }
  __syncthreads();

  // coalesced write-out: hdn (ushort4)
#pragma unroll
  for (int rep = 0; rep < 2; ++rep) {
    int idx = tid + rep * 1024;
    int row = idx >> 5, c4 = idx & 31;
    int gr = base + row;
    if (gr < n) {
      ushort4 hv4 = *(const ushort4*)&aggS[row * 132 + c4 * 4];
      *(ushort4*)(hdn + (size_t)gr * 128 + c4 * 4) = hv4;
    }
  }
}

// ---------------- decoder: 6-layer hd-max staging + MFMA + rdinv un-scale ----------------

__global__ __launch_bounds__(256) void decoder_mfma(
    const unsigned short* __restrict__ h0, const unsigned short* __restrict__ h1,
    const unsigned short* __restrict__ h2, const unsigned short* __restrict__ h3,
    const unsigned short* __restrict__ h4, const unsigned short* __restrict__ h5,
    const float* __restrict__ rdinv,
    const int4* __restrict__ wdpk, const float* __restrict__ bh,
    const float* __restrict__ Wo, const float* __restrict__ bo,
    float* __restrict__ out, int n) {
  __shared__ unsigned short zS[64 * 132];
  int tid = threadIdx.x;
  int base = blockIdx.x * 64;
  const unsigned short* hp[6] = {h0, h1, h2, h3, h4, h5};
#pragma unroll
  for (int rep = 0; rep < 8; ++rep) {
    int idx = tid + rep * 256;
    int row = idx >> 5, c4 = idx & 31;
    int gr = base + row; if (gr > n - 1) gr = n - 1;
    size_t o = (size_t)gr * 128 + c4 * 4;
    ushort4 uu[6];
#pragma unroll
    for (int li = 0; li < 6; ++li) uu[li] = *(const ushort4*)(hp[li] + o);
    ushort4 m = uu[0];
#pragma unroll
    for (int li = 1; li < 6; ++li) {
      m.x = (bf2f(uu[li].x) > bf2f(m.x)) ? uu[li].x : m.x;
      m.y = (bf2f(uu[li].y) > bf2f(m.y)) ? uu[li].y : m.y;
      m.z = (bf2f(uu[li].z) > bf2f(m.z)) ? uu[li].z : m.z;
      m.w = (bf2f(uu[li].w) > bf2f(m.w)) ? uu[li].w : m.w;
    }
    *(ushort4*)&zS[row * 132 + c4 * 4] = m;
  }
  __syncthreads();
  int w = tid >> 6, l = tid & 63;
  int lr = l & 15, lg = l >> 4;
  f32x4 acc[4];
#pragma unroll
  for (int ft = 0; ft < 4; ++ft) { acc[ft][0] = 0.f; acc[ft][1] = 0.f; acc[ft][2] = 0.f; acc[ft][3] = 0.f; }
#pragma unroll
  for (int ks = 0; ks < 4; ++ks) {
    U8 fz;
    int boff = (w * 16 + lr) * 132 + ks * 32 + lg * 4;
    fz.h[0] = *(const ushort4*)&zS[boff];
    fz.h[1] = *(const ushort4*)&zS[boff + 16];
#pragma unroll
    for (int ft = 0; ft < 4; ++ft) {
      U8 bw; bw.q = wdpk[(ks * 4 + ft) * 64 + l];
      acc[ft] = __builtin_amdgcn_mfma_f32_16x16x32_bf16(fz.v, bw.v, acc[ft], 0, 0, 0);
    }
  }
  int rowb = base + w * 16 + lg * 4;
  float rr[4];
#pragma unroll
  for (int e = 0; e < 4; ++e) {
    int gr = rowb + e; if (gr > n - 1) gr = n - 1;
    rr[e] = rdinv[gr];
  }
  float s[4] = {0.f, 0.f, 0.f, 0.f};
#pragma unroll
  for (int ft = 0; ft < 4; ++ft) {
    int j = ft * 16 + lr;
    float bj = bh[j], wj = Wo[j];
#pragma unroll
    for (int e = 0; e < 4; ++e) {
      float hid = fmaxf(fmaf(acc[ft][e], rr[e], bj), 0.f);
      s[e] = fmaf(hid, wj, s[e]);
    }
  }
#pragma unroll
  for (int e = 0; e < 4; ++e) {
    float v = s[e];
    v += __shfl_xor(v, 1);
    v += __shfl_xor(v, 2);
    v += __shfl_xor(v, 4);
    v += __shfl_xor(v, 8);
    if (lr == 0) {
      int gr = rowb + e;
      if (gr < n) out[gr] = v + bo[0];
    }
  }
}

// ---------------- launch ----------------

extern "C" void kernel_launch(void* const* d_in, const int* in_sizes, int n_in,
                              void* d_out, int out_size, void* d_ws, size_t ws_size,
                              hipStream_t stream) {
  const float* x       = (const float*)d_in[0];
  const int*   edge    = (const int*)d_in[1];
  const float* W_embed = (const float*)d_in[2];
  const float* b_embed = (const float*)d_in[3];
  const float* w_ih    = (const float*)d_in[4];
  const float* w_hh    = (const float*)d_in[5];
  const float* b_ih    = (const float*)d_in[6];
  const float* b_hh    = (const float*)d_in[7];
  const float* W_hid   = (const float*)d_in[8];
  const float* b_hid   = (const float*)d_in[9];
  const float* W_out   = (const float*)d_in[10];
  const float* b_out   = (const float*)d_in[11];
  float* out = (float*)d_out;

  const int N = in_sizes[0] / 3;       // 50000
  const int E = in_sizes[1] / 2;       // 600000
  const int NB = (N + SCAN_CHUNK - 1) / SCAN_CHUNK;

  char* ws = (char*)d_ws;
  size_t off = 0;
  auto alloc = [&](size_t bytes) -> void* {
    void* p = ws + off;
    off = (off + bytes + 511) & ~(size_t)511;
    return p;
  };
  int*   deg     = (int*)alloc((size_t)N * 4);
  float* dinv    = (float*)alloc((size_t)N * 4);
  float* rdinv   = (float*)alloc((size_t)N * 4);
  int*   row_ptr = (int*)alloc((size_t)(N + 1) * 4);
  int*   cursor  = (int*)alloc((size_t)N * 4);
  int*   bsum    = (int*)alloc((size_t)NB * 4);
  int*   boff    = (int*)alloc((size_t)NB * 4);
  int*   srcv    = (int*)alloc((size_t)(E + 8) * 4);
  unsigned short* wpack  = (unsigned short*)alloc((size_t)491520 * 2);
  unsigned short* wdpack = (unsigned short*)alloc((size_t)8192 * 2);
  unsigned short* aggb   = (unsigned short*)alloc((size_t)N * 128 * 2);
  unsigned short* hbs[6];
  for (int i = 0; i < 6; ++i) hbs[i] = (unsigned short*)alloc((size_t)N * 128 * 2);

  const int* erow = edge;
  const int* ecol = edge + E;

  hipMemsetAsync(deg, 0, (size_t)N * 4, stream);
  count_deg<<<(E + NTHREADS - 1) / NTHREADS, NTHREADS, 0, stream>>>(ecol, deg, E);
  block_reduce<<<NB, NTHREADS, 0, stream>>>(deg, bsum, dinv, rdinv, N);
  scan_partials<<<1, 64, 0, stream>>>(bsum, boff, row_ptr + N, NB);
  scan_final<<<NB, NTHREADS, 0, stream>>>(deg, boff, row_ptr, cursor, N);
  scatter_edges<<<(E + NTHREADS - 1) / NTHREADS, NTHREADS, 0, stream>>>(erow, ecol, cursor, srcv, E);

  pack_weights<<<(491520 + NTHREADS - 1) / NTHREADS, NTHREADS, 0, stream>>>(w_ih, w_hh, wpack);
  pack_whid<<<32, NTHREADS, 0, stream>>>(W_hid, wdpack);

  encoder<<<(N + 3) / 4, NTHREADS, 0, stream>>>(x, W_embed, b_embed, dinv, hbs[0], N);

  for (int l = 0; l < 5; ++l) {
    aggregate<<<(N + 3) / 4, NTHREADS, 0, stream>>>(row_ptr, srcv, dinv, hbs[l], aggb, N);
    gru_mfma<<<(N + 63) / 64, 1024, 0, stream>>>(
        aggb, hbs[l], hbs[l + 1], dinv, rdinv,
        (const int4*)(wpack + (size_t)l * 98304),
        b_ih + (size_t)l * 384, b_hh + (size_t)l * 384, N);
  }

  decoder_mfma<<<(N + 63) / 64, NTHREADS, 0, stream>>>(
      hbs[0], hbs[1], hbs[2], hbs[3], hbs[4], hbs[5], rdinv,
      (const int4*)wdpack, b_hid, W_out, b_out, out, N);
}

// Round 14
// 397.028 us; speedup vs baseline: 1.5374x; 1.0438x over previous
//
#include <hip/hip_runtime.h>
#include <math.h>

// DrBC: encoder -> 5x(aggregate ; gru_mfma) -> decoder(6-layer max + MFMA).
// FLAT layout [N][128] bf16, state PRE-SCALED hd = dinv*h (aggregate = pure row-sum),
// GRU/decoder un-scale rows by rdinv = sqrt(deg+1). Gate math uses HW rcp/exp
// (sigmoid = rcp(1+exp(-x)), tanh = 1-2*rcp(1+exp(2x))) instead of IEEE div + libm.

#define NTHREADS 256
#define SCAN_CHUNK 1024

typedef __attribute__((ext_vector_type(8))) short s16x8;
typedef __attribute__((ext_vector_type(4))) float f32x4;

union U8 { s16x8 v; ushort4 h[2]; int4 q; };

__device__ __forceinline__ unsigned short f2bf(float f) {
  union { float f; unsigned u; } x; x.f = f;
  unsigned u = x.u + 0x7FFFu + ((x.u >> 16) & 1u);  // RNE to bf16
  return (unsigned short)(u >> 16);
}
__device__ __forceinline__ float bf2f(unsigned short s) {
  union { unsigned u; float f; } x; x.u = ((unsigned)s) << 16;
  return x.f;
}
__device__ __forceinline__ float fast_sigmoid(float x) {
  return __builtin_amdgcn_rcpf(1.f + __expf(-x));
}
__device__ __forceinline__ float fast_tanh(float x) {
  return 1.f - 2.f * __builtin_amdgcn_rcpf(1.f + __expf(2.f * x));
}

// ---------------- CSR build ----------------

__global__ void count_deg(const int* __restrict__ col, int* deg, int E) {
  int e = blockIdx.x * NTHREADS + threadIdx.x;
  if (e < E) atomicAdd(&deg[col[e]], 1);
}

__global__ void block_reduce(const int* __restrict__ cnt, int* __restrict__ bsum,
                             float* __restrict__ dinv, float* __restrict__ rdinv, int n) {
  __shared__ int red[NTHREADS];
  int b = blockIdx.x, t = threadIdx.x;
  int base = b * SCAN_CHUNK + t * 4;
  int s = 0;
#pragma unroll
  for (int i = 0; i < 4; ++i) {
    int idx = base + i;
    if (idx < n) {
      int c = cnt[idx];
      s += c;
      dinv[idx] = rsqrtf((float)c + 1.0f);
      rdinv[idx] = sqrtf((float)c + 1.0f);
    }
  }
  red[t] = s;
  __syncthreads();
  for (int off = NTHREADS / 2; off > 0; off >>= 1) {
    if (t < off) red[t] += red[t + off];
    __syncthreads();
  }
  if (t == 0) bsum[b] = red[0];
}

// 64 threads (1 wave); nb <= 64.
__global__ void scan_partials(const int* __restrict__ bsum, int* __restrict__ boff,
                              int* __restrict__ row_ptr_n, int nb) {
  int t = threadIdx.x;
  int s = (t < nb) ? bsum[t] : 0;
  int orig = s;
#pragma unroll
  for (int off = 1; off < 64; off <<= 1) {
    int v = __shfl_up(s, off);
    if (t >= off) s += v;
  }
  if (t < nb) boff[t] = s - orig;
  if (t == nb - 1) *row_ptr_n = s;
}

__global__ void scan_final(const int* __restrict__ cnt, const int* __restrict__ boff,
                           int* __restrict__ row_ptr, int* __restrict__ cursor, int n) {
  __shared__ int sums[NTHREADS];
  int b = blockIdx.x, t = threadIdx.x;
  int base = b * SCAN_CHUNK + t * 4;
  int v[4];
  int s = 0;
#pragma unroll
  for (int i = 0; i < 4; ++i) { int idx = base + i; v[i] = (idx < n) ? cnt[idx] : 0; s += v[i]; }
  sums[t] = s;
  __syncthreads();
  for (int off = 1; off < NTHREADS; off <<= 1) {
    int a = (t >= off) ? sums[t - off] : 0;
    __syncthreads();
    sums[t] += a;
    __syncthreads();
  }
  int run = boff[b] + sums[t] - s;
#pragma unroll
  for (int i = 0; i < 4; ++i) {
    int idx = base + i;
    if (idx < n) { row_ptr[idx] = run; cursor[idx] = run; }
    run += v[i];
  }
}

// scatter: src index only (weights fully factorized into prescaled state)
__global__ void scatter_edges(const int* __restrict__ row, const int* __restrict__ col,
                              int* cursor, int* __restrict__ src, int E) {
  int e = blockIdx.x * NTHREADS + threadIdx.x;
  if (e >= E) return;
  int r = row[e], c = col[e];
  int p = atomicAdd(&cursor[c], 1);
  src[p] = r;
}

// ---------------- weight packs: MFMA B-fragment order, bf16 ----------------
// k-map sigma(e,lane) = 32*ks + (e&3) + 4*((lane>>4)&3) + 16*(e>>2); same map on the
// A side -> result invariant to sigma's exact correctness.

__global__ void pack_weights(const float* __restrict__ w_ih, const float* __restrict__ w_hh,
                             unsigned short* __restrict__ out) {
  int idx = blockIdx.x * NTHREADS + threadIdx.x;
  if (idx >= 491520) return;
  int e = idx & 7;
  int lane = (idx >> 3) & 63;
  int ft = (idx >> 9) & 7;
  int v = idx >> 12;
  int g = v % 6;
  int u = v / 6;
  int ks = u & 3;
  int layer = u >> 2;
  int k = 32 * ks + (e & 3) + 4 * ((lane >> 4) & 3) + 16 * (e >> 2);
  int j = 16 * ft + (lane & 15);
  const float* src = (g < 3) ? w_ih : w_hh;
  int gate = g % 3;
  float val = src[(size_t)layer * 49152 + (size_t)(gate * 128 + j) * 128 + k];
  out[idx] = f2bf(val);
}

// W_hid [64][128] -> [ks][ft][lane][e] bf16
__global__ void pack_whid(const float* __restrict__ W_hid, unsigned short* __restrict__ out) {
  int idx = blockIdx.x * NTHREADS + threadIdx.x;
  if (idx >= 8192) return;
  int e = idx & 7;
  int lane = (idx >> 3) & 63;
  int ft = (idx >> 9) & 3;
  int ks = idx >> 11;
  int k = 32 * ks + (e & 3) + 4 * ((lane >> 4) & 3) + 16 * (e >> 2);
  int j = 16 * ft + (lane & 15);
  out[idx] = f2bf(W_hid[j * 128 + k]);
}

// ---------------- encoder: hd0 = dinv * l2norm(relu(xW+b)) (flat bf16) ----------------

__global__ void encoder(const float* __restrict__ x, const float* __restrict__ W,
                        const float* __restrict__ b, const float* __restrict__ dinv,
                        unsigned short* __restrict__ hd, int n) {
  int node = blockIdx.x * 4 + (threadIdx.x >> 6);
  int lane = threadIdx.x & 63;
  if (node >= n) return;
  float x0 = x[node * 3 + 0], x1 = x[node * 3 + 1], x2 = x[node * 3 + 2];
  int j0 = lane, j1 = lane + 64;
  float v0 = fmaxf(fmaf(W[j0 * 3 + 2], x2, fmaf(W[j0 * 3 + 1], x1, fmaf(W[j0 * 3], x0, b[j0]))), 0.f);
  float v1 = fmaxf(fmaf(W[j1 * 3 + 2], x2, fmaf(W[j1 * 3 + 1], x1, fmaf(W[j1 * 3], x0, b[j1]))), 0.f);
  float ss = v0 * v0 + v1 * v1;
#pragma unroll
  for (int sh = 32; sh > 0; sh >>= 1) ss += __shfl_down(ss, sh);
  ss = __shfl(ss, 0);
  float sc = 1.0f / fmaxf(sqrtf(ss), 1e-12f);
  float dv = dinv[node];
  size_t base = (size_t)node * 128;
  hd[base + j0] = f2bf(v0 * sc * dv);
  hd[base + j1] = f2bf(v1 * sc * dv);
}

// ---------------- aggregation: flat row gather, uniform clamped 8-batches ----------------
// agg[c] = dinv[c] * sum_e hd[src_e]   (no per-edge weights: state is prescaled)

__global__ void aggregate(const int* __restrict__ row_ptr, const int* __restrict__ src,
                          const float* __restrict__ dinv, const unsigned short* __restrict__ hd,
                          unsigned short* __restrict__ aggb, int n) {
  int node = blockIdx.x * 4 + (threadIdx.x >> 6);
  int lane = threadIdx.x & 63;
  if (node >= n) return;
  const unsigned* hw = (const unsigned*)hd;
  int pb = row_ptr[node], pe = row_ptr[node + 1];
  float aL[4] = {0.f, 0.f, 0.f, 0.f};
  float aH[4] = {0.f, 0.f, 0.f, 0.f};
  for (int p = pb; p < pe; p += 8) {
    unsigned u[8]; float wv[8];
#pragma unroll
    for (int i = 0; i < 8; ++i) {
      int q = p + i;
      int ok = q < pe;
      int s = src[ok ? q : pb];
      wv[i] = ok ? 1.f : 0.f;
      u[i] = hw[(size_t)s * 64 + lane];
    }
#pragma unroll
    for (int i = 0; i < 8; ++i) {
      aL[i & 3] = fmaf(wv[i], bf2f((unsigned short)(u[i] & 0xFFFFu)), aL[i & 3]);
      aH[i & 3] = fmaf(wv[i], bf2f((unsigned short)(u[i] >> 16)), aH[i & 3]);
    }
  }
  float dc = dinv[node];
  float a0 = ((aL[0] + aL[1]) + (aL[2] + aL[3])) * dc;
  float a1 = ((aH[0] + aH[1]) + (aH[2] + aH[3])) * dc;
  unsigned o = ((unsigned)f2bf(a1) << 16) | (unsigned)f2bf(a0);
  ((unsigned*)(aggb + (size_t)node * 128))[lane] = o;
}

// ---------------- GRU layer via MFMA (flat prescaled I/O, fast gate math) ----------------
// 1024 threads = 16 waves, 64 nodes/block. h-GEMM runs on hd; rows un-scaled by rdinv.

__global__ __launch_bounds__(1024) void gru_mfma(
    const unsigned short* __restrict__ aggb, const unsigned short* __restrict__ hdc,
    unsigned short* __restrict__ hdn, const float* __restrict__ dinv,
    const float* __restrict__ rdinv,
    const int4* __restrict__ wpk, const float* __restrict__ bih,
    const float* __restrict__ bhh, int n) {
  __shared__ unsigned short aggS[64 * 132];
  __shared__ unsigned short hS[64 * 132];
  __shared__ float partS[64 * 8];
  __shared__ float scv[64];
  __shared__ float dS[64], rS[64];
  int tid = threadIdx.x;
  int base = blockIdx.x * 64;
  int w = tid >> 6, l = tid & 63;
  int mh = w & 1, fh = w >> 1;
  int lr = l & 15, lg = l >> 4;
  int jj = fh * 16 + lr;

  if (tid < 64) {
    int gr = base + tid; if (gr > n - 1) gr = n - 1;
    dS[tid] = dinv[gr];
    rS[tid] = rdinv[gr];
  }
#pragma unroll
  for (int rep = 0; rep < 2; ++rep) {
    int idx = tid + rep * 1024;
    int row = idx >> 5, c4 = idx & 31;
    int gr = base + row; if (gr > n - 1) gr = n - 1;
    ushort4 ua = *(const ushort4*)(aggb + (size_t)gr * 128 + c4 * 4);
    ushort4 uh = *(const ushort4*)(hdc + (size_t)gr * 128 + c4 * 4);
    *(ushort4*)&aggS[row * 132 + c4 * 4] = ua;
    *(ushort4*)&hS[row * 132 + c4 * 4] = uh;
  }
  __syncthreads();

  f32x4 acc[2][6];
#pragma unroll
  for (int mt = 0; mt < 2; ++mt)
#pragma unroll
    for (int g = 0; g < 6; ++g) { acc[mt][g][0] = 0.f; acc[mt][g][1] = 0.f; acc[mt][g][2] = 0.f; acc[mt][g][3] = 0.f; }

#pragma unroll
  for (int ks = 0; ks < 4; ++ks) {
    U8 fa[2], fhh[2];
#pragma unroll
    for (int mt = 0; mt < 2; ++mt) {
      int boff = (mh * 32 + mt * 16 + lr) * 132 + ks * 32 + lg * 4;
      fa[mt].h[0] = *(const ushort4*)&aggS[boff];
      fa[mt].h[1] = *(const ushort4*)&aggS[boff + 16];
      fhh[mt].h[0] = *(const ushort4*)&hS[boff];
      fhh[mt].h[1] = *(const ushort4*)&hS[boff + 16];
    }
#pragma unroll
    for (int g = 0; g < 6; ++g) {
      U8 bw; bw.q = wpk[((ks * 6 + g) * 8 + fh) * 64 + l];
      const U8& a0 = (g < 3) ? fa[0] : fhh[0];
      const U8& a1 = (g < 3) ? fa[1] : fhh[1];
      acc[0][g] = __builtin_amdgcn_mfma_f32_16x16x32_bf16(a0.v, bw.v, acc[0][g], 0, 0, 0);
      acc[1][g] = __builtin_amdgcn_mfma_f32_16x16x32_bf16(a1.v, bw.v, acc[1][g], 0, 0, 0);
    }
  }

  float br = bih[jj], bz = bih[128 + jj], bn = bih[256 + jj];
  float cr = bhh[jj], cz = bhh[128 + jj], cn = bhh[256 + jj];
  float hn_out[2][4];
#pragma unroll
  for (int mt = 0; mt < 2; ++mt)
#pragma unroll
    for (int e = 0; e < 4; ++e) {
      int row = mh * 32 + mt * 16 + lg * 4 + e;
      float rr = rS[row];
      float ir = acc[mt][0][e], iz = acc[mt][1][e], inn = acc[mt][2][e];
      float hr = acc[mt][3][e] * rr, hz = acc[mt][4][e] * rr, hnv = acc[mt][5][e] * rr;
      float r = fast_sigmoid(ir + hr + br + cr);
      float z = fast_sigmoid(iz + hz + bz + cz);
      float ng = fast_tanh(inn + bn + r * (hnv + cn));
      float hv = bf2f(hS[row * 132 + jj]) * rr;
      float hn = (1.f - z) * ng + z * hv;
      hn_out[mt][e] = hn;
      float p = hn * hn;
      p += __shfl_xor(p, 1);
      p += __shfl_xor(p, 2);
      p += __shfl_xor(p, 4);
      p += __shfl_xor(p, 8);
      if (lr == 0) partS[row * 8 + fh] = p;
    }
  __syncthreads();
  if (tid < 64) {
    float ss = 0.f;
#pragma unroll
    for (int f = 0; f < 8; ++f) ss += partS[tid * 8 + f];
    scv[tid] = rsqrtf(fmaxf(ss, 1e-24f));
  }
  __syncthreads();

  // normalize + prescale -> bf16 staged into dead aggS
#pragma unroll
  for (int mt = 0; mt < 2; ++mt)
#pragma unroll
    for (int e = 0; e < 4; ++e) {
      int row = mh * 32 + mt * 16 + lg * 4 + e;
      aggS[row * 132 + jj] = f2bf(hn_out[mt][e] * scv[row] * dS[row]);
    }
  __syncthreads();

  // coalesced write-out: hdn (ushort4)
#pragma unroll
  for (int rep = 0; rep < 2; ++rep) {
    int idx = tid + rep * 1024;
    int row = idx >> 5, c4 = idx & 31;
    int gr = base + row;
    if (gr < n) {
      ushort4 hv4 = *(const ushort4*)&aggS[row * 132 + c4 * 4];
      *(ushort4*)(hdn + (size_t)gr * 128 + c4 * 4) = hv4;
    }
  }
}

// ---------------- decoder: 6-layer hd-max staging + MFMA + rdinv un-scale ----------------

__global__ __launch_bounds__(256) void decoder_mfma(
    const unsigned short* __restrict__ h0, const unsigned short* __restrict__ h1,
    const unsigned short* __restrict__ h2, const unsigned short* __restrict__ h3,
    const unsigned short* __restrict__ h4, const unsigned short* __restrict__ h5,
    const float* __restrict__ rdinv,
    const int4* __restrict__ wdpk, const float* __restrict__ bh,
    const float* __restrict__ Wo, const float* __restrict__ bo,
    float* __restrict__ out, int n) {
  __shared__ unsigned short zS[64 * 132];
  int tid = threadIdx.x;
  int base = blockIdx.x * 64;
  const unsigned short* hp[6] = {h0, h1, h2, h3, h4, h5};
#pragma unroll
  for (int rep = 0; rep < 8; ++rep) {
    int idx = tid + rep * 256;
    int row = idx >> 5, c4 = idx & 31;
    int gr = base + row; if (gr > n - 1) gr = n - 1;
    size_t o = (size_t)gr * 128 + c4 * 4;
    ushort4 uu[6];
#pragma unroll
    for (int li = 0; li < 6; ++li) uu[li] = *(const ushort4*)(hp[li] + o);
    ushort4 m = uu[0];
#pragma unroll
    for (int li = 1; li < 6; ++li) {
      m.x = (bf2f(uu[li].x) > bf2f(m.x)) ? uu[li].x : m.x;
      m.y = (bf2f(uu[li].y) > bf2f(m.y)) ? uu[li].y : m.y;
      m.z = (bf2f(uu[li].z) > bf2f(m.z)) ? uu[li].z : m.z;
      m.w = (bf2f(uu[li].w) > bf2f(m.w)) ? uu[li].w : m.w;
    }
    *(ushort4*)&zS[row * 132 + c4 * 4] = m;
  }
  __syncthreads();
  int w = tid >> 6, l = tid & 63;
  int lr = l & 15, lg = l >> 4;
  f32x4 acc[4];
#pragma unroll
  for (int ft = 0; ft < 4; ++ft) { acc[ft][0] = 0.f; acc[ft][1] = 0.f; acc[ft][2] = 0.f; acc[ft][3] = 0.f; }
#pragma unroll
  for (int ks = 0; ks < 4; ++ks) {
    U8 fz;
    int boff = (w * 16 + lr) * 132 + ks * 32 + lg * 4;
    fz.h[0] = *(const ushort4*)&zS[boff];
    fz.h[1] = *(const ushort4*)&zS[boff + 16];
#pragma unroll
    for (int ft = 0; ft < 4; ++ft) {
      U8 bw; bw.q = wdpk[(ks * 4 + ft) * 64 + l];
      acc[ft] = __builtin_amdgcn_mfma_f32_16x16x32_bf16(fz.v, bw.v, acc[ft], 0, 0, 0);
    }
  }
  int rowb = base + w * 16 + lg * 4;
  float rr[4];
#pragma unroll
  for (int e = 0; e < 4; ++e) {
    int gr = rowb + e; if (gr > n - 1) gr = n - 1;
    rr[e] = rdinv[gr];
  }
  float s[4] = {0.f, 0.f, 0.f, 0.f};
#pragma unroll
  for (int ft = 0; ft < 4; ++ft) {
    int j = ft * 16 + lr;
    float bj = bh[j], wj = Wo[j];
#pragma unroll
    for (int e = 0; e < 4; ++e) {
      float hid = fmaxf(fmaf(acc[ft][e], rr[e], bj), 0.f);
      s[e] = fmaf(hid, wj, s[e]);
    }
  }
#pragma unroll
  for (int e = 0; e < 4; ++e) {
    float v = s[e];
    v += __shfl_xor(v, 1);
    v += __shfl_xor(v, 2);
    v += __shfl_xor(v, 4);
    v += __shfl_xor(v, 8);
    if (lr == 0) {
      int gr = rowb + e;
      if (gr < n) out[gr] = v + bo[0];
    }
  }
}

// ---------------- launch ----------------

extern "C" void kernel_launch(void* const* d_in, const int* in_sizes, int n_in,
                              void* d_out, int out_size, void* d_ws, size_t ws_size,
                              hipStream_t stream) {
  const float* x       = (const float*)d_in[0];
  const int*   edge    = (const int*)d_in[1];
  const float* W_embed = (const float*)d_in[2];
  const float* b_embed = (const float*)d_in[3];
  const float* w_ih    = (const float*)d_in[4];
  const float* w_hh    = (const float*)d_in[5];
  const float* b_ih    = (const float*)d_in[6];
  const float* b_hh    = (const float*)d_in[7];
  const float* W_hid   = (const float*)d_in[8];
  const float* b_hid   = (const float*)d_in[9];
  const float* W_out   = (const float*)d_in[10];
  const float* b_out   = (const float*)d_in[11];
  float* out = (float*)d_out;

  const int N = in_sizes[0] / 3;       // 50000
  const int E = in_sizes[1] / 2;       // 600000
  const int NB = (N + SCAN_CHUNK - 1) / SCAN_CHUNK;

  char* ws = (char*)d_ws;
  size_t off = 0;
  auto alloc = [&](size_t bytes) -> void* {
    void* p = ws + off;
    off = (off + bytes + 511) & ~(size_t)511;
    return p;
  };
  int*   deg     = (int*)alloc((size_t)N * 4);
  float* dinv    = (float*)alloc((size_t)N * 4);
  float* rdinv   = (float*)alloc((size_t)N * 4);
  int*   row_ptr = (int*)alloc((size_t)(N + 1) * 4);
  int*   cursor  = (int*)alloc((size_t)N * 4);
  int*   bsum    = (int*)alloc((size_t)NB * 4);
  int*   boff    = (int*)alloc((size_t)NB * 4);
  int*   srcv    = (int*)alloc((size_t)(E + 8) * 4);
  unsigned short* wpack  = (unsigned short*)alloc((size_t)491520 * 2);
  unsigned short* wdpack = (unsigned short*)alloc((size_t)8192 * 2);
  unsigned short* aggb   = (unsigned short*)alloc((size_t)N * 128 * 2);
  unsigned short* hbs[6];
  for (int i = 0; i < 6; ++i) hbs[i] = (unsigned short*)alloc((size_t)N * 128 * 2);

  const int* erow = edge;
  const int* ecol = edge + E;

  hipMemsetAsync(deg, 0, (size_t)N * 4, stream);
  count_deg<<<(E + NTHREADS - 1) / NTHREADS, NTHREADS, 0, stream>>>(ecol, deg, E);
  block_reduce<<<NB, NTHREADS, 0, stream>>>(deg, bsum, dinv, rdinv, N);
  scan_partials<<<1, 64, 0, stream>>>(bsum, boff, row_ptr + N, NB);
  scan_final<<<NB, NTHREADS, 0, stream>>>(deg, boff, row_ptr, cursor, N);
  scatter_edges<<<(E + NTHREADS - 1) / NTHREADS, NTHREADS, 0, stream>>>(erow, ecol, cursor, srcv, E);

  pack_weights<<<(491520 + NTHREADS - 1) / NTHREADS, NTHREADS, 0, stream>>>(w_ih, w_hh, wpack);
  pack_whid<<<32, NTHREADS, 0, stream>>>(W_hid, wdpack);

  encoder<<<(N + 3) / 4, NTHREADS, 0, stream>>>(x, W_embed, b_embed, dinv, hbs[0], N);

  for (int l = 0; l < 5; ++l) {
    aggregate<<<(N + 3) / 4, NTHREADS, 0, stream>>>(row_ptr, srcv, dinv, hbs[l], aggb, N);
    gru_mfma<<<(N + 63) / 64, 1024, 0, stream>>>(
        aggb, hbs[l], hbs[l + 1], dinv, rdinv,
        (const int4*)(wpack + (size_t)l * 98304),
        b_ih + (size_t)l * 384, b_hh + (size_t)l * 384, N);
  }

  decoder_mfma<<<(N + 63) / 64, NTHREADS, 0, stream>>>(
      hbs[0], hbs[1], hbs[2], hbs[3], hbs[4], hbs[5], rdinv,
      (const int4*)wdpack, b_hid, W_out, b_out, out, N);
}